// Round 1
// baseline (5777.990 us; speedup 1.0000x reference)
//
#include <hip/hip_runtime.h>

// GraphSAGE forward: lin+relu -> SAGEConv(mean)+relu -> SAGEConv(mean) -> log_softmax
// N=100000 nodes, E=1.6M edges, dims 128 -> 128 -> 128 -> 64, fp32 throughout.
//
// Round 0 strategy:
//  - 3 fused GEMM kernels (fp32 vector ALU; no fp32 MFMA on CDNA4)
//  - edge aggregation via gather + f32 atomicAdd scatter (CSR planned if this dominates)
//  - mean division fused into GEMM row staging (scale by 1/max(deg,1))
//  - ws: h1 (51.2MB) | h2 (51.2MB) | agg (51.2MB) | deg (0.4MB) = 154MB

#define KDIM 128

__global__ void zero_f4(float* __restrict__ p, long n) {
    long i = (long)blockIdx.x * blockDim.x + threadIdx.x;
    long stride = (long)gridDim.x * blockDim.x;
    float4* p4 = (float4*)p;
    long n4 = n >> 2;
    for (long j = i; j < n4; j += stride) p4[j] = make_float4(0.f, 0.f, 0.f, 0.f);
    if (i == 0) for (long j = n4 << 2; j < n; ++j) p[j] = 0.f;
}

// 32 threads per edge; each thread handles 4 contiguous feature columns.
__global__ __launch_bounds__(256) void scatter_add(
    const float* __restrict__ h, const int* __restrict__ ei,
    float* __restrict__ agg, float* __restrict__ deg, int nE)
{
    long gid = (long)blockIdx.x * 256 + threadIdx.x;
    int e = (int)(gid >> 5);
    int c = (int)(gid & 31);
    if (e >= nE) return;
    int src = ei[e];
    int dst = ei[nE + e];
    const float4 v = *(const float4*)(h + (long)src * KDIM + c * 4);
    float* a = agg + (long)dst * KDIM + c * 4;
    atomicAdd(a + 0, v.x);
    atomicAdd(a + 1, v.y);
    atomicAdd(a + 2, v.z);
    atomicAdd(a + 3, v.w);
    if (deg != nullptr && c == 0) atomicAdd(deg + dst, 1.0f);
}

// out[i][:] = act( scale_i * (A[i] @ Wl^T) + bias + (B[i] @ Wr^T) )
// scale_i = 1/max(deg[i],1) if degp else 1.  ACT: 0 none, 1 relu, 2 log_softmax.
// K fixed at 128, split into two 64-halves staged in LDS (80KB -> 2 blocks/CU).
template<int M, bool HAS_B, int ACT>
__global__ __launch_bounds__(256, 2) void fused_gemm(
    const float* __restrict__ A, const float* __restrict__ degp,
    const float* __restrict__ B,
    const float* __restrict__ Wl, const float* __restrict__ Wr,
    const float* __restrict__ bias, float* __restrict__ out, int N)
{
    constexpr int TGX = M / 4;        // col groups (32 or 16)
    constexpr int TGY = 256 / TGX;    // row groups (8 or 16)
    constexpr int RPT = 32 / TGY;     // rows per thread (4 or 2)
    constexpr int KH = 64;            // k half
    constexpr int SMASK = (M / 4) - 1;

    __shared__ __attribute__((aligned(16))) float wlT[KH * M];
    __shared__ __attribute__((aligned(16))) float wrT[HAS_B ? KH * M : 4];
    __shared__ __attribute__((aligned(16))) float xa[32 * KH];
    __shared__ __attribute__((aligned(16))) float xb[HAS_B ? 32 * KH : 4];

    const int t = threadIdx.x;
    const int tx = t % TGX;
    const int ty = t / TGX;
    const int row0 = blockIdx.x * 32;

    float acc[RPT][4];
    {
        const float4 bv = *(const float4*)(bias + tx * 4);
        #pragma unroll
        for (int r = 0; r < RPT; ++r) {
            acc[r][0] = bv.x; acc[r][1] = bv.y; acc[r][2] = bv.z; acc[r][3] = bv.w;
        }
    }

    for (int kb = 0; kb < 2; ++kb) {
        const int k0 = kb * KH;
        if (kb) __syncthreads();

        // ---- stage weights transposed with XOR slot swizzle ----
        {
            constexpr int WF4 = KH * M / 4;   // float4 loads (k-contiguous)
            const float4* Wl4 = (const float4*)Wl;
            for (int i4 = t; i4 < WF4; i4 += 256) {
                int j  = i4 >> 4;             // KH/4 = 16 float4 per output row
                int kc = i4 & 15;
                float4 w = Wl4[j * (KDIM / 4) + (k0 >> 2) + kc];
                const float* wf = (const float*)&w;
                #pragma unroll
                for (int q = 0; q < 4; ++q) {
                    int kl = kc * 4 + q;
                    int slot = (j >> 2) ^ (kl & SMASK);
                    wlT[kl * M + slot * 4 + (j & 3)] = wf[q];
                }
            }
            if (HAS_B) {
                const float4* Wr4 = (const float4*)Wr;
                for (int i4 = t; i4 < WF4; i4 += 256) {
                    int j  = i4 >> 4;
                    int kc = i4 & 15;
                    float4 w = Wr4[j * (KDIM / 4) + (k0 >> 2) + kc];
                    const float* wf = (const float*)&w;
                    #pragma unroll
                    for (int q = 0; q < 4; ++q) {
                        int kl = kc * 4 + q;
                        int slot = (j >> 2) ^ (kl & SMASK);
                        wrT[kl * M + slot * 4 + (j & 3)] = wf[q];
                    }
                }
            }
        }

        // ---- stage input rows (scaled by 1/max(deg,1) for the agg operand) ----
        {
            const float4* A4 = (const float4*)A;
            for (int i4 = t; i4 < 32 * KH / 4; i4 += 256) {
                int r  = i4 >> 4;
                int kc = i4 & 15;
                int row = row0 + r;
                float4 v = make_float4(0.f, 0.f, 0.f, 0.f);
                float s = 1.f;
                if (row < N) {
                    v = A4[(long)row * (KDIM / 4) + (k0 >> 2) + kc];
                    if (degp) s = 1.f / fmaxf(degp[row], 1.f);
                }
                *(float4*)(xa + r * KH + kc * 4) =
                    make_float4(v.x * s, v.y * s, v.z * s, v.w * s);
            }
            if (HAS_B) {
                const float4* B4 = (const float4*)B;
                for (int i4 = t; i4 < 32 * KH / 4; i4 += 256) {
                    int r  = i4 >> 4;
                    int kc = i4 & 15;
                    int row = row0 + r;
                    float4 v = make_float4(0.f, 0.f, 0.f, 0.f);
                    if (row < N) v = B4[(long)row * (KDIM / 4) + (k0 >> 2) + kc];
                    *(float4*)(xb + r * KH + kc * 4) = v;
                }
            }
        }
        __syncthreads();

        // ---- compute ----
        #pragma unroll 4
        for (int kk = 0; kk < KH; kk += 4) {
            float ac[RPT][4];
            #pragma unroll
            for (int r = 0; r < RPT; ++r) {
                float4 tmp = *(const float4*)(xa + (ty * RPT + r) * KH + kk);
                ac[r][0] = tmp.x; ac[r][1] = tmp.y; ac[r][2] = tmp.z; ac[r][3] = tmp.w;
            }
            float4 wl4v[4];
            #pragma unroll
            for (int q = 0; q < 4; ++q) {
                int kl = kk + q;
                wl4v[q] = *(const float4*)(wlT + kl * M + ((tx ^ (kl & SMASK)) << 2));
            }
            #pragma unroll
            for (int q = 0; q < 4; ++q) {
                const float4 wv = wl4v[q];
                #pragma unroll
                for (int r = 0; r < RPT; ++r) {
                    const float av = ac[r][q];
                    acc[r][0] = fmaf(av, wv.x, acc[r][0]);
                    acc[r][1] = fmaf(av, wv.y, acc[r][1]);
                    acc[r][2] = fmaf(av, wv.z, acc[r][2]);
                    acc[r][3] = fmaf(av, wv.w, acc[r][3]);
                }
            }
            if (HAS_B) {
                float bc[RPT][4];
                #pragma unroll
                for (int r = 0; r < RPT; ++r) {
                    float4 tmp = *(const float4*)(xb + (ty * RPT + r) * KH + kk);
                    bc[r][0] = tmp.x; bc[r][1] = tmp.y; bc[r][2] = tmp.z; bc[r][3] = tmp.w;
                }
                float4 wr4v[4];
                #pragma unroll
                for (int q = 0; q < 4; ++q) {
                    int kl = kk + q;
                    wr4v[q] = *(const float4*)(wrT + kl * M + ((tx ^ (kl & SMASK)) << 2));
                }
                #pragma unroll
                for (int q = 0; q < 4; ++q) {
                    const float4 wv = wr4v[q];
                    #pragma unroll
                    for (int r = 0; r < RPT; ++r) {
                        const float av = bc[r][q];
                        acc[r][0] = fmaf(av, wv.x, acc[r][0]);
                        acc[r][1] = fmaf(av, wv.y, acc[r][1]);
                        acc[r][2] = fmaf(av, wv.z, acc[r][2]);
                        acc[r][3] = fmaf(av, wv.w, acc[r][3]);
                    }
                }
            }
        }
    }

    // ---- epilogue ----
    #pragma unroll
    for (int r = 0; r < RPT; ++r) {
        const int row = row0 + ty * RPT + r;
        if (ACT == 2) {
            // log_softmax across M=64 cols held by TGX=16 consecutive lanes
            float m = fmaxf(fmaxf(acc[r][0], acc[r][1]), fmaxf(acc[r][2], acc[r][3]));
            #pragma unroll
            for (int mask = 1; mask < 16; mask <<= 1)
                m = fmaxf(m, __shfl_xor(m, mask));
            float s = expf(acc[r][0] - m) + expf(acc[r][1] - m) +
                      expf(acc[r][2] - m) + expf(acc[r][3] - m);
            #pragma unroll
            for (int mask = 1; mask < 16; mask <<= 1)
                s += __shfl_xor(s, mask);
            const float L = logf(s);
            if (row < N) {
                float4 o = make_float4(acc[r][0] - m - L, acc[r][1] - m - L,
                                       acc[r][2] - m - L, acc[r][3] - m - L);
                *(float4*)(out + (long)row * M + tx * 4) = o;
            }
        } else {
            if (row < N) {
                float4 o = make_float4(acc[r][0], acc[r][1], acc[r][2], acc[r][3]);
                if (ACT == 1) {
                    o.x = fmaxf(o.x, 0.f); o.y = fmaxf(o.y, 0.f);
                    o.z = fmaxf(o.z, 0.f); o.w = fmaxf(o.w, 0.f);
                }
                *(float4*)(out + (long)row * M + tx * 4) = o;
            }
        }
    }
}

extern "C" void kernel_launch(void* const* d_in, const int* in_sizes, int n_in,
                              void* d_out, int out_size, void* d_ws, size_t ws_size,
                              hipStream_t stream) {
    const float* x     = (const float*)d_in[0];
    const int*   ei    = (const int*)d_in[1];   // [2, E] int32 (JAX canonicalizes int64->int32)
    const float* lin_W = (const float*)d_in[2];
    const float* lin_b = (const float*)d_in[3];
    const float* c1_Wl = (const float*)d_in[4];
    const float* c1_bl = (const float*)d_in[5];
    const float* c1_Wr = (const float*)d_in[6];
    const float* c2_Wl = (const float*)d_in[7];
    const float* c2_bl = (const float*)d_in[8];
    const float* c2_Wr = (const float*)d_in[9];
    float* out = (float*)d_out;

    const int N = in_sizes[0] / KDIM;
    const int E = in_sizes[1] / 2;

    float* h1  = (float*)d_ws;                   // N*128
    float* h2  = h1 + (size_t)N * KDIM;          // N*128
    float* agg = h2 + (size_t)N * KDIM;          // N*128
    float* deg = agg + (size_t)N * KDIM;         // N  (contiguous after agg)

    const int nb = (N + 31) / 32;
    const int sb = (int)(((long)E * 32 + 255) / 256);

    // layer 1: h1 = relu(x @ lin_W^T + lin_b)
    fused_gemm<128, false, 1><<<nb, 256, 0, stream>>>(
        x, nullptr, nullptr, lin_W, nullptr, lin_b, h1, N);

    // conv1 aggregation: zero agg+deg, scatter h1 by dst, count deg
    zero_f4<<<2048, 256, 0, stream>>>(agg, (long)N * KDIM + N);
    scatter_add<<<sb, 256, 0, stream>>>(h1, ei, agg, deg, E);

    // conv1: h2 = relu(mean @ c1_Wl^T + c1_bl + h1 @ c1_Wr^T)
    fused_gemm<128, true, 1><<<nb, 256, 0, stream>>>(
        agg, deg, h1, c1_Wl, c1_Wr, c1_bl, h2, N);

    // conv2 aggregation (deg reused)
    zero_f4<<<2048, 256, 0, stream>>>(agg, (long)N * KDIM);
    scatter_add<<<sb, 256, 0, stream>>>(h2, ei, agg, nullptr, E);

    // conv2 + log_softmax -> d_out
    fused_gemm<64, true, 2><<<nb, 256, 0, stream>>>(
        agg, deg, h2, c2_Wl, c2_Wr, c2_bl, out, N);
}

// Round 2
// 871.401 us; speedup vs baseline: 6.6307x; 6.6307x over previous
//
#include <hip/hip_runtime.h>

// GraphSAGE forward: lin+relu -> SAGEConv(mean)+relu -> SAGEConv(mean) -> log_softmax
// N=100000 nodes, E=1.6M edges, dims 128 -> 128 -> 128 -> 64, fp32 throughout.
//
// Round 2: atomic scatter (3.3GB HBM atomic-RMW writes/pass, 2763us each) replaced by
// CSR-by-dst build (once) + gather-sum per conv (no float atomics).
//  ws: h1 | h2 | agg (3x51.2MB) | degf | offs | cursor | perm | deg_i  (~162MB)

#define KDIM 128

__global__ void zero_f4(float* __restrict__ p, long n) {
    long i = (long)blockIdx.x * blockDim.x + threadIdx.x;
    long stride = (long)gridDim.x * blockDim.x;
    float4* p4 = (float4*)p;
    long n4 = n >> 2;
    for (long j = i; j < n4; j += stride) p4[j] = make_float4(0.f, 0.f, 0.f, 0.f);
    if (i == 0) for (long j = n4 << 2; j < n; ++j) p[j] = 0.f;
}

__global__ __launch_bounds__(256) void compute_deg(
    const int* __restrict__ ei, int* __restrict__ deg_i, int E)
{
    int e = blockIdx.x * 256 + threadIdx.x;
    if (e < E) atomicAdd(&deg_i[ei[E + e]], 1);
}

// Single-workgroup exclusive scan of deg_i[0..n) -> offs[0..n], plus
// cursor = offs copy and degf = (float)deg. 256 threads x 16 elems/tile.
__global__ __launch_bounds__(256) void exscan_deg(
    const int* __restrict__ deg_i, int* __restrict__ offs,
    int* __restrict__ cursor, float* __restrict__ degf, int n)
{
    __shared__ int wsum[4];
    __shared__ int carry_s;
    const int t = threadIdx.x;
    const int lane = t & 63, wid = t >> 6;
    if (t == 0) carry_s = 0;
    __syncthreads();
    const int VPT = 16;
    const int TILE = 256 * VPT;
    for (int base = 0; base < n; base += TILE) {
        const int idx = base + t * VPT;
        int v[VPT];
        if (idx + VPT <= n) {
            #pragma unroll
            for (int q = 0; q < VPT / 4; ++q) {
                int4 a = *(const int4*)(deg_i + idx + q * 4);
                v[q * 4 + 0] = a.x; v[q * 4 + 1] = a.y;
                v[q * 4 + 2] = a.z; v[q * 4 + 3] = a.w;
            }
        } else {
            #pragma unroll
            for (int k = 0; k < VPT; ++k) v[k] = (idx + k < n) ? deg_i[idx + k] : 0;
        }
        int sum = 0;
        #pragma unroll
        for (int k = 0; k < VPT; ++k) sum += v[k];
        int incl = sum;
        #pragma unroll
        for (int d = 1; d < 64; d <<= 1) {
            int u = __shfl_up(incl, d);
            if (lane >= d) incl += u;
        }
        if (lane == 63) wsum[wid] = incl;
        __syncthreads();
        int woff = 0;
        #pragma unroll
        for (int w = 0; w < 4; ++w) if (w < wid) woff += wsum[w];
        const int total = wsum[0] + wsum[1] + wsum[2] + wsum[3];
        int excl = carry_s + woff + (incl - sum);
        #pragma unroll
        for (int k = 0; k < VPT; ++k) {
            if (idx + k < n) {
                offs[idx + k] = excl;
                cursor[idx + k] = excl;
                degf[idx + k] = (float)v[k];
                excl += v[k];
            }
        }
        __syncthreads();
        if (t == 0) carry_s += total;
        __syncthreads();
    }
    if (t == 0) offs[n] = carry_s;
}

__global__ __launch_bounds__(256) void fill_perm(
    const int* __restrict__ ei, int* __restrict__ cursor,
    int* __restrict__ perm, int E)
{
    int e = blockIdx.x * 256 + threadIdx.x;
    if (e >= E) return;
    int src = ei[e];
    int dst = ei[E + e];
    int pos = atomicAdd(&cursor[dst], 1);
    perm[pos] = src;
}

// One wave per node: agg[node][:] = sum_{j in CSR[node]} h[j][:]
__global__ __launch_bounds__(256) void csr_gather_sum(
    const float* __restrict__ h, const int* __restrict__ offs,
    const int* __restrict__ perm, float* __restrict__ agg, int N)
{
    const int node = blockIdx.x * 4 + (threadIdx.x >> 6);
    if (node >= N) return;
    const int lane = threadIdx.x & 63;
    const int b = offs[node], e = offs[node + 1];
    float2 a0 = {0.f, 0.f}, a1 = {0.f, 0.f};
    int i = b;
    for (; i + 2 <= e; i += 2) {
        const int s0 = perm[i], s1 = perm[i + 1];
        const float2 v0 = *(const float2*)(h + (long)s0 * KDIM + lane * 2);
        const float2 v1 = *(const float2*)(h + (long)s1 * KDIM + lane * 2);
        a0.x += v0.x; a0.y += v0.y;
        a1.x += v1.x; a1.y += v1.y;
    }
    if (i < e) {
        const int s0 = perm[i];
        const float2 v0 = *(const float2*)(h + (long)s0 * KDIM + lane * 2);
        a0.x += v0.x; a0.y += v0.y;
    }
    *(float2*)(agg + (long)node * KDIM + lane * 2) =
        make_float2(a0.x + a1.x, a0.y + a1.y);
}

// out[i][:] = act( scale_i * (A[i] @ Wl^T) + bias + (B[i] @ Wr^T) )
// scale_i = 1/max(deg[i],1) if degp else 1.  ACT: 0 none, 1 relu, 2 log_softmax.
template<int M, bool HAS_B, int ACT>
__global__ __launch_bounds__(256, 2) void fused_gemm(
    const float* __restrict__ A, const float* __restrict__ degp,
    const float* __restrict__ B,
    const float* __restrict__ Wl, const float* __restrict__ Wr,
    const float* __restrict__ bias, float* __restrict__ out, int N)
{
    constexpr int TGX = M / 4;        // col groups (32 or 16)
    constexpr int TGY = 256 / TGX;    // row groups (8 or 16)
    constexpr int RPT = 32 / TGY;     // rows per thread (4 or 2)
    constexpr int KH = 64;            // k half
    constexpr int SMASK = (M / 4) - 1;

    __shared__ __attribute__((aligned(16))) float wlT[KH * M];
    __shared__ __attribute__((aligned(16))) float wrT[HAS_B ? KH * M : 4];
    __shared__ __attribute__((aligned(16))) float xa[32 * KH];
    __shared__ __attribute__((aligned(16))) float xb[HAS_B ? 32 * KH : 4];

    const int t = threadIdx.x;
    const int tx = t % TGX;
    const int ty = t / TGX;
    const int row0 = blockIdx.x * 32;

    float acc[RPT][4];
    {
        const float4 bv = *(const float4*)(bias + tx * 4);
        #pragma unroll
        for (int r = 0; r < RPT; ++r) {
            acc[r][0] = bv.x; acc[r][1] = bv.y; acc[r][2] = bv.z; acc[r][3] = bv.w;
        }
    }

    for (int kb = 0; kb < 2; ++kb) {
        const int k0 = kb * KH;
        if (kb) __syncthreads();

        // ---- stage weights transposed with XOR slot swizzle ----
        {
            constexpr int WF4 = KH * M / 4;
            const float4* Wl4 = (const float4*)Wl;
            for (int i4 = t; i4 < WF4; i4 += 256) {
                int j  = i4 >> 4;
                int kc = i4 & 15;
                float4 w = Wl4[j * (KDIM / 4) + (k0 >> 2) + kc];
                const float* wf = (const float*)&w;
                #pragma unroll
                for (int q = 0; q < 4; ++q) {
                    int kl = kc * 4 + q;
                    int slot = (j >> 2) ^ (kl & SMASK);
                    wlT[kl * M + slot * 4 + (j & 3)] = wf[q];
                }
            }
            if (HAS_B) {
                const float4* Wr4 = (const float4*)Wr;
                for (int i4 = t; i4 < WF4; i4 += 256) {
                    int j  = i4 >> 4;
                    int kc = i4 & 15;
                    float4 w = Wr4[j * (KDIM / 4) + (k0 >> 2) + kc];
                    const float* wf = (const float*)&w;
                    #pragma unroll
                    for (int q = 0; q < 4; ++q) {
                        int kl = kc * 4 + q;
                        int slot = (j >> 2) ^ (kl & SMASK);
                        wrT[kl * M + slot * 4 + (j & 3)] = wf[q];
                    }
                }
            }
        }

        // ---- stage input rows (scaled by 1/max(deg,1) for the agg operand) ----
        {
            const float4* A4 = (const float4*)A;
            for (int i4 = t; i4 < 32 * KH / 4; i4 += 256) {
                int r  = i4 >> 4;
                int kc = i4 & 15;
                int row = row0 + r;
                float4 v = make_float4(0.f, 0.f, 0.f, 0.f);
                float s = 1.f;
                if (row < N) {
                    v = A4[(long)row * (KDIM / 4) + (k0 >> 2) + kc];
                    if (degp) s = 1.f / fmaxf(degp[row], 1.f);
                }
                *(float4*)(xa + r * KH + kc * 4) =
                    make_float4(v.x * s, v.y * s, v.z * s, v.w * s);
            }
            if (HAS_B) {
                const float4* B4 = (const float4*)B;
                for (int i4 = t; i4 < 32 * KH / 4; i4 += 256) {
                    int r  = i4 >> 4;
                    int kc = i4 & 15;
                    int row = row0 + r;
                    float4 v = make_float4(0.f, 0.f, 0.f, 0.f);
                    if (row < N) v = B4[(long)row * (KDIM / 4) + (k0 >> 2) + kc];
                    *(float4*)(xb + r * KH + kc * 4) = v;
                }
            }
        }
        __syncthreads();

        // ---- compute ----
        #pragma unroll 4
        for (int kk = 0; kk < KH; kk += 4) {
            float ac[RPT][4];
            #pragma unroll
            for (int r = 0; r < RPT; ++r) {
                float4 tmp = *(const float4*)(xa + (ty * RPT + r) * KH + kk);
                ac[r][0] = tmp.x; ac[r][1] = tmp.y; ac[r][2] = tmp.z; ac[r][3] = tmp.w;
            }
            float4 wl4v[4];
            #pragma unroll
            for (int q = 0; q < 4; ++q) {
                int kl = kk + q;
                wl4v[q] = *(const float4*)(wlT + kl * M + ((tx ^ (kl & SMASK)) << 2));
            }
            #pragma unroll
            for (int q = 0; q < 4; ++q) {
                const float4 wv = wl4v[q];
                #pragma unroll
                for (int r = 0; r < RPT; ++r) {
                    const float av = ac[r][q];
                    acc[r][0] = fmaf(av, wv.x, acc[r][0]);
                    acc[r][1] = fmaf(av, wv.y, acc[r][1]);
                    acc[r][2] = fmaf(av, wv.z, acc[r][2]);
                    acc[r][3] = fmaf(av, wv.w, acc[r][3]);
                }
            }
            if (HAS_B) {
                float bc[RPT][4];
                #pragma unroll
                for (int r = 0; r < RPT; ++r) {
                    float4 tmp = *(const float4*)(xb + (ty * RPT + r) * KH + kk);
                    bc[r][0] = tmp.x; bc[r][1] = tmp.y; bc[r][2] = tmp.z; bc[r][3] = tmp.w;
                }
                float4 wr4v[4];
                #pragma unroll
                for (int q = 0; q < 4; ++q) {
                    int kl = kk + q;
                    wr4v[q] = *(const float4*)(wrT + kl * M + ((tx ^ (kl & SMASK)) << 2));
                }
                #pragma unroll
                for (int q = 0; q < 4; ++q) {
                    const float4 wv = wr4v[q];
                    #pragma unroll
                    for (int r = 0; r < RPT; ++r) {
                        const float av = bc[r][q];
                        acc[r][0] = fmaf(av, wv.x, acc[r][0]);
                        acc[r][1] = fmaf(av, wv.y, acc[r][1]);
                        acc[r][2] = fmaf(av, wv.z, acc[r][2]);
                        acc[r][3] = fmaf(av, wv.w, acc[r][3]);
                    }
                }
            }
        }
    }

    // ---- epilogue ----
    #pragma unroll
    for (int r = 0; r < RPT; ++r) {
        const int row = row0 + ty * RPT + r;
        if (ACT == 2) {
            float m = fmaxf(fmaxf(acc[r][0], acc[r][1]), fmaxf(acc[r][2], acc[r][3]));
            #pragma unroll
            for (int mask = 1; mask < 16; mask <<= 1)
                m = fmaxf(m, __shfl_xor(m, mask));
            float s = expf(acc[r][0] - m) + expf(acc[r][1] - m) +
                      expf(acc[r][2] - m) + expf(acc[r][3] - m);
            #pragma unroll
            for (int mask = 1; mask < 16; mask <<= 1)
                s += __shfl_xor(s, mask);
            const float L = logf(s);
            if (row < N) {
                float4 o = make_float4(acc[r][0] - m - L, acc[r][1] - m - L,
                                       acc[r][2] - m - L, acc[r][3] - m - L);
                *(float4*)(out + (long)row * M + tx * 4) = o;
            }
        } else {
            if (row < N) {
                float4 o = make_float4(acc[r][0], acc[r][1], acc[r][2], acc[r][3]);
                if (ACT == 1) {
                    o.x = fmaxf(o.x, 0.f); o.y = fmaxf(o.y, 0.f);
                    o.z = fmaxf(o.z, 0.f); o.w = fmaxf(o.w, 0.f);
                }
                *(float4*)(out + (long)row * M + tx * 4) = o;
            }
        }
    }
}

extern "C" void kernel_launch(void* const* d_in, const int* in_sizes, int n_in,
                              void* d_out, int out_size, void* d_ws, size_t ws_size,
                              hipStream_t stream) {
    const float* x     = (const float*)d_in[0];
    const int*   ei    = (const int*)d_in[1];
    const float* lin_W = (const float*)d_in[2];
    const float* lin_b = (const float*)d_in[3];
    const float* c1_Wl = (const float*)d_in[4];
    const float* c1_bl = (const float*)d_in[5];
    const float* c1_Wr = (const float*)d_in[6];
    const float* c2_Wl = (const float*)d_in[7];
    const float* c2_bl = (const float*)d_in[8];
    const float* c2_Wr = (const float*)d_in[9];
    float* out = (float*)d_out;

    const int N = in_sizes[0] / KDIM;
    const int E = in_sizes[1] / 2;

    float* h1   = (float*)d_ws;                  // N*128 f32
    float* h2   = h1 + (size_t)N * KDIM;         // N*128 f32
    float* agg  = h2 + (size_t)N * KDIM;         // N*128 f32
    float* degf = agg + (size_t)N * KDIM;        // N f32
    int*   offs   = (int*)(degf + N);            // N+1 int
    int*   cursor = offs + (N + 1);              // N int
    int*   deg_i  = cursor + N;                  // N int
    int*   perm   = deg_i + N;                   // E int

    const int nb = (N + 31) / 32;
    const int eb = (E + 255) / 256;

    // ---- CSR build (graph shared by both convs) ----
    zero_f4<<<256, 256, 0, stream>>>((float*)deg_i, N);
    compute_deg<<<eb, 256, 0, stream>>>(ei, deg_i, E);
    exscan_deg<<<1, 256, 0, stream>>>(deg_i, offs, cursor, degf, N);
    fill_perm<<<eb, 256, 0, stream>>>(ei, cursor, perm, E);

    // layer 1: h1 = relu(x @ lin_W^T + lin_b)
    fused_gemm<128, false, 1><<<nb, 256, 0, stream>>>(
        x, nullptr, nullptr, lin_W, nullptr, lin_b, h1, N);

    // conv1: agg = sum_{j->i} h1[j]; h2 = relu(agg/deg @ c1_Wl^T + c1_bl + h1 @ c1_Wr^T)
    csr_gather_sum<<<(N + 3) / 4, 256, 0, stream>>>(h1, offs, perm, agg, N);
    fused_gemm<128, true, 1><<<nb, 256, 0, stream>>>(
        agg, degf, h1, c1_Wl, c1_Wr, c1_bl, h2, N);

    // conv2
    csr_gather_sum<<<(N + 3) / 4, 256, 0, stream>>>(h2, offs, perm, agg, N);
    fused_gemm<64, true, 2><<<nb, 256, 0, stream>>>(
        agg, degf, h2, c2_Wl, c2_Wr, c2_bl, out, N);
}

// Round 3
// 533.346 us; speedup vs baseline: 10.8335x; 1.6338x over previous
//
#include <hip/hip_runtime.h>

// GraphSAGE forward: lin+relu -> SAGEConv(mean)+relu -> SAGEConv(mean) -> log_softmax
// N=100000, E=1.6M, dims 128 -> 128 -> 128 -> 64.
//
// Round 3: GEMMs moved to bf16 MFMA (16x16x32, fp32 accum), intermediates bf16
// (halves gather traffic), mean fused into gather epilogue. CSR build unchanged.
// ws: xb16 | h1 | h2 | agg (4 x 25.6MB bf16) | wpack(128KB) | degf | offs | cursor | deg_i | perm

#define KDIM 128

using bf16x8 = __attribute__((ext_vector_type(8))) short;
using f32x4  = __attribute__((ext_vector_type(4))) float;

__device__ __forceinline__ unsigned short f2bf_u(float f) {
    unsigned u = __float_as_uint(f);
    u += 0x7fffu + ((u >> 16) & 1u);
    return (unsigned short)(u >> 16);
}
__device__ __forceinline__ unsigned packbf2(float a, float b) {
    return (unsigned)f2bf_u(a) | ((unsigned)f2bf_u(b) << 16);
}
__device__ __forceinline__ float bflo(unsigned u) { return __uint_as_float(u << 16); }
__device__ __forceinline__ float bfhi(unsigned u) { return __uint_as_float(u & 0xffff0000u); }

__device__ __forceinline__ void gload_lds16(const short* g, short* l) {
    __builtin_amdgcn_global_load_lds(
        (const __attribute__((address_space(1))) unsigned int*)g,
        (__attribute__((address_space(3))) unsigned int*)l, 16, 0, 0);
}

__global__ void zero_i(int* __restrict__ p, int n) {
    int i = blockIdx.x * 256 + threadIdx.x;
    if (i < n) p[i] = 0;
}

__global__ __launch_bounds__(256) void compute_deg(
    const int* __restrict__ ei, int* __restrict__ deg_i, int E)
{
    int e = blockIdx.x * 256 + threadIdx.x;
    if (e < E) atomicAdd(&deg_i[ei[E + e]], 1);
}

// Single-workgroup exclusive scan of deg_i -> offs, cursor copy, degf float copy.
__global__ __launch_bounds__(256) void exscan_deg(
    const int* __restrict__ deg_i, int* __restrict__ offs,
    int* __restrict__ cursor, float* __restrict__ degf, int n)
{
    __shared__ int wsum[4];
    __shared__ int carry_s;
    const int t = threadIdx.x;
    const int lane = t & 63, wid = t >> 6;
    if (t == 0) carry_s = 0;
    __syncthreads();
    const int VPT = 16;
    const int TILE = 256 * VPT;
    for (int base = 0; base < n; base += TILE) {
        const int idx = base + t * VPT;
        int v[VPT];
        if (idx + VPT <= n) {
            #pragma unroll
            for (int q = 0; q < VPT / 4; ++q) {
                int4 a = *(const int4*)(deg_i + idx + q * 4);
                v[q * 4 + 0] = a.x; v[q * 4 + 1] = a.y;
                v[q * 4 + 2] = a.z; v[q * 4 + 3] = a.w;
            }
        } else {
            #pragma unroll
            for (int k = 0; k < VPT; ++k) v[k] = (idx + k < n) ? deg_i[idx + k] : 0;
        }
        int sum = 0;
        #pragma unroll
        for (int k = 0; k < VPT; ++k) sum += v[k];
        int incl = sum;
        #pragma unroll
        for (int d = 1; d < 64; d <<= 1) {
            int u = __shfl_up(incl, d);
            if (lane >= d) incl += u;
        }
        if (lane == 63) wsum[wid] = incl;
        __syncthreads();
        int woff = 0;
        #pragma unroll
        for (int w = 0; w < 4; ++w) if (w < wid) woff += wsum[w];
        const int total = wsum[0] + wsum[1] + wsum[2] + wsum[3];
        int excl = carry_s + woff + (incl - sum);
        #pragma unroll
        for (int k = 0; k < VPT; ++k) {
            if (idx + k < n) {
                offs[idx + k] = excl;
                cursor[idx + k] = excl;
                degf[idx + k] = (float)v[k];
                excl += v[k];
            }
        }
        __syncthreads();
        if (t == 0) carry_s += total;
        __syncthreads();
    }
    if (t == 0) offs[n] = carry_s;
}

__global__ __launch_bounds__(256) void fill_perm(
    const int* __restrict__ ei, int* __restrict__ cursor,
    int* __restrict__ perm, int E)
{
    int e = blockIdx.x * 256 + threadIdx.x;
    if (e >= E) return;
    int src = ei[e];
    int dst = ei[E + e];
    int pos = atomicAdd(&cursor[dst], 1);
    perm[pos] = src;
}

__global__ __launch_bounds__(256) void cvt_f32_bf16(
    const float* __restrict__ x, short* __restrict__ y, long n4)
{
    long i = (long)blockIdx.x * 256 + threadIdx.x;
    long stride = (long)gridDim.x * 256;
    const float4* x4 = (const float4*)x;
    for (long j = i; j < n4; j += stride) {
        float4 v = x4[j];
        uint2 o;
        o.x = packbf2(v.x, v.y);
        o.y = packbf2(v.z, v.w);
        *(uint2*)(y + j * 4) = o;
    }
}

// Pack 5 weight matrices into MFMA B-fragment layout:
// wp[ks][cf][lane][j] = bf16(W[cf*16 + (lane&15)][ks*32 + (lane>>4)*8 + j])
__global__ __launch_bounds__(256) void pack_weights(
    const float* __restrict__ Wlin, const float* __restrict__ Wc1l,
    const float* __restrict__ Wc1r, const float* __restrict__ Wc2l,
    const float* __restrict__ Wc2r, short* __restrict__ wp)
{
    int idx = blockIdx.x * 256 + threadIdx.x;   // 0..65535
    if (idx >= 65536) return;
    const float* W; short* dst; int off, ncf;
    if (idx < 16384)      { W = Wlin; dst = wp;         off = idx;         ncf = 8; }
    else if (idx < 32768) { W = Wc1l; dst = wp + 16384; off = idx - 16384; ncf = 8; }
    else if (idx < 49152) { W = Wc1r; dst = wp + 32768; off = idx - 32768; ncf = 8; }
    else if (idx < 57344) { W = Wc2l; dst = wp + 49152; off = idx - 49152; ncf = 4; }
    else                  { W = Wc2r; dst = wp + 57344; off = idx - 57344; ncf = 4; }
    int j    = off & 7;
    int lane = (off >> 3) & 63;
    int cf   = (off >> 9) & (ncf - 1);
    int ks   = off >> ((ncf == 8) ? 12 : 11);
    int m = cf * 16 + (lane & 15);
    int k = ks * 32 + ((lane >> 4) << 3) + j;
    dst[off] = (short)f2bf_u(W[m * KDIM + k]);
}

// 2 nodes per wave (32 lanes/node, 8B per lane): agg[n] = bf16(sum_{j} h[j] / max(deg,1))
__global__ __launch_bounds__(256) void csr_gather_mean(
    const short* __restrict__ h, const int* __restrict__ offs,
    const int* __restrict__ perm, const float* __restrict__ degf,
    short* __restrict__ agg, int N)
{
    const int node = blockIdx.x * 8 + (threadIdx.x >> 5);
    if (node >= N) return;
    const int hl = threadIdx.x & 31;
    const int b = offs[node], e = offs[node + 1];
    float a0 = 0.f, a1 = 0.f, a2 = 0.f, a3 = 0.f;
    float b0 = 0.f, b1 = 0.f, b2 = 0.f, b3 = 0.f;
    int i = b;
    for (; i + 2 <= e; i += 2) {
        const int s0 = perm[i], s1 = perm[i + 1];
        const uint2 u = *(const uint2*)(h + (long)s0 * KDIM + hl * 4);
        const uint2 v = *(const uint2*)(h + (long)s1 * KDIM + hl * 4);
        a0 += bflo(u.x); a1 += bfhi(u.x); a2 += bflo(u.y); a3 += bfhi(u.y);
        b0 += bflo(v.x); b1 += bfhi(v.x); b2 += bflo(v.y); b3 += bfhi(v.y);
    }
    if (i < e) {
        const uint2 u = *(const uint2*)(h + (long)perm[i] * KDIM + hl * 4);
        a0 += bflo(u.x); a1 += bfhi(u.x); a2 += bflo(u.y); a3 += bfhi(u.y);
    }
    const float inv = 1.f / fmaxf(degf[node], 1.f);
    uint2 o;
    o.x = packbf2((a0 + b0) * inv, (a1 + b1) * inv);
    o.y = packbf2((a2 + b2) * inv, (a3 + b3) * inv);
    *(uint2*)(agg + (long)node * KDIM + hl * 4) = o;
}

// out = act( A @ WA^T + bias [+ B @ WB^T] ).  A,B bf16 row-major [N][128].
// Weights pre-packed in fragment layout. 64-row tile/block, 4 waves.
// NCF=8 (out 128 cols): wave w -> col-frags {2w,2w+1}, row-frags 0..3.
// NCF=4 (out  64 cols): wave w -> row-frag w, col-frags 0..3.
// ACT: 1 relu -> bf16 out; 2 log_softmax -> f32 out.
template<int NCF, bool HAS_B, int ACT>
__global__ __launch_bounds__(256) void gemm_mfma(
    const short* __restrict__ A, const short* __restrict__ B,
    const short* __restrict__ wpA, const short* __restrict__ wpB,
    const float* __restrict__ bias, void* __restrict__ outp, int N)
{
    constexpr int CFW = (NCF == 8) ? 2 : 4;
    constexpr int RFW = (NCF == 8) ? 4 : 1;
    __shared__ __attribute__((aligned(16))) short xa[64 * KDIM];
    __shared__ __attribute__((aligned(16))) short xb[HAS_B ? 64 * KDIM : 8];

    const int t = threadIdx.x;
    const int w = t >> 6, lane = t & 63;
    const int row0 = blockIdx.x * 64;
    const int cf0 = (NCF == 8) ? w * 2 : 0;
    const int rf0 = (NCF == 8) ? 0 : w;

    // ---- weight B-fragments -> registers (coalesced 16B/lane) ----
    bf16x8 bwA[4][CFW];
    bf16x8 bwB[HAS_B ? 4 : 1][HAS_B ? CFW : 1];
    #pragma unroll
    for (int ks = 0; ks < 4; ++ks)
        #pragma unroll
        for (int c = 0; c < CFW; ++c) {
            bwA[ks][c] = *(const bf16x8*)(wpA + (((ks * NCF) + cf0 + c) * 64 + lane) * 8);
            if (HAS_B)
                bwB[ks][c] = *(const bf16x8*)(wpB + (((ks * NCF) + cf0 + c) * 64 + lane) * 8);
        }

    // ---- stage A (and B) 64x128 tiles: global_load_lds, XOR-swizzled source ----
    // LDS granule (row, s) holds global granule (s ^ (row&7)); granule = 8 bf16 = 16B.
    #pragma unroll
    for (int ii = 0; ii < 4; ++ii) {
        const int i = w * 4 + ii;
        const int rl = i * 4 + (lane >> 4);
        const int grow = min(row0 + rl, N - 1);
        const int gs = (lane & 15) ^ (rl & 7);
        gload_lds16(A + (long)grow * KDIM + gs * 8, &xa[i * 512]);
        if (HAS_B) gload_lds16(B + (long)grow * KDIM + gs * 8, &xb[i * 512]);
    }

    // ---- accumulators init with bias (col = (cf0+c)*16 + (lane&15)) ----
    f32x4 acc[RFW][CFW];
    #pragma unroll
    for (int c = 0; c < CFW; ++c) {
        const float bv = bias[(cf0 + c) * 16 + (lane & 15)];
        #pragma unroll
        for (int rf = 0; rf < RFW; ++rf)
            acc[rf][c] = f32x4{bv, bv, bv, bv};
    }

    __syncthreads();   // drains global_load_lds (vmcnt) + barrier

    // ---- MFMA: K = 4 steps of 32 ----
    #pragma unroll
    for (int ks = 0; ks < 4; ++ks) {
        #pragma unroll
        for (int rf = 0; rf < RFW; ++rf) {
            const int rl = (rf0 + rf) * 16 + (lane & 15);
            const int s = (ks * 4 + (lane >> 4)) ^ (rl & 7);
            const bf16x8 a = *(const bf16x8*)(xa + rl * KDIM + s * 8);
            #pragma unroll
            for (int c = 0; c < CFW; ++c)
                acc[rf][c] = __builtin_amdgcn_mfma_f32_16x16x32_bf16(
                    a, bwA[ks][c], acc[rf][c], 0, 0, 0);
            if (HAS_B) {
                const bf16x8 bb = *(const bf16x8*)(xb + rl * KDIM + s * 8);
                #pragma unroll
                for (int c = 0; c < CFW; ++c)
                    acc[rf][c] = __builtin_amdgcn_mfma_f32_16x16x32_bf16(
                        bb, bwB[ks][c], acc[rf][c], 0, 0, 0);
            }
        }
    }

    // ---- epilogue ----
    // C/D layout: col = lane&15, row = (lane>>4)*4 + reg  [m89-verified]
    if (ACT != 2) {
        short* out = (short*)outp;
        #pragma unroll
        for (int rf = 0; rf < RFW; ++rf)
            #pragma unroll
            for (int c = 0; c < CFW; ++c)
                #pragma unroll
                for (int q = 0; q < 4; ++q) {
                    const int row = row0 + (rf0 + rf) * 16 + (lane >> 4) * 4 + q;
                    if (row < N) {
                        float v = acc[rf][c][q];
                        if (ACT == 1) v = fmaxf(v, 0.f);
                        out[(long)row * (NCF * 16) + (cf0 + c) * 16 + (lane & 15)] =
                            (short)f2bf_u(v);
                    }
                }
    } else {
        // NCF==4: RFW=1; lane holds cols {c*16 + (lane&15)}, rows w*16 + (lane>>4)*4 + q
        float* out = (float*)outp;
        #pragma unroll
        for (int q = 0; q < 4; ++q) {
            float m = fmaxf(fmaxf(acc[0][0][q], acc[0][1][q]),
                            fmaxf(acc[0][2][q], acc[0][3][q]));
            #pragma unroll
            for (int mk = 1; mk < 16; mk <<= 1) m = fmaxf(m, __shfl_xor(m, mk));
            float s = 0.f;
            #pragma unroll
            for (int c = 0; c < 4; ++c) s += expf(acc[0][c][q] - m);
            #pragma unroll
            for (int mk = 1; mk < 16; mk <<= 1) s += __shfl_xor(s, mk);
            const float L = m + logf(s);
            const int row = row0 + rf0 * 16 + (lane >> 4) * 4 + q;
            if (row < N) {
                #pragma unroll
                for (int c = 0; c < 4; ++c)
                    out[(long)row * 64 + c * 16 + (lane & 15)] = acc[0][c][q] - L;
            }
        }
    }
}

extern "C" void kernel_launch(void* const* d_in, const int* in_sizes, int n_in,
                              void* d_out, int out_size, void* d_ws, size_t ws_size,
                              hipStream_t stream) {
    const float* x     = (const float*)d_in[0];
    const int*   ei    = (const int*)d_in[1];
    const float* lin_W = (const float*)d_in[2];
    const float* lin_b = (const float*)d_in[3];
    const float* c1_Wl = (const float*)d_in[4];
    const float* c1_bl = (const float*)d_in[5];
    const float* c1_Wr = (const float*)d_in[6];
    const float* c2_Wl = (const float*)d_in[7];
    const float* c2_bl = (const float*)d_in[8];
    const float* c2_Wr = (const float*)d_in[9];
    float* out = (float*)d_out;

    const int N = in_sizes[0] / KDIM;
    const int E = in_sizes[1] / 2;

    short* xb16 = (short*)d_ws;                  // N*128 bf16
    short* h1   = xb16 + (size_t)N * KDIM;       // N*128 bf16
    short* h2   = h1 + (size_t)N * KDIM;         // N*128 bf16
    short* aggb = h2 + (size_t)N * KDIM;         // N*128 bf16
    short* wp   = aggb + (size_t)N * KDIM;       // 65536 bf16 (packed weights)
    float* degf = (float*)(wp + 65536);          // N f32
    int* offs   = (int*)(degf + N);              // N+1
    int* cursor = offs + (N + 1);                // N
    int* deg_i  = cursor + N;                    // N
    int* perm   = deg_i + N;                     // E

    const int eb = (E + 255) / 256;
    const int nb = (N + 63) / 64;
    const int gb = (N + 7) / 8;

    // ---- CSR build (graph shared by both convs) ----
    zero_i<<<(N + 255) / 256, 256, 0, stream>>>(deg_i, N);
    compute_deg<<<eb, 256, 0, stream>>>(ei, deg_i, E);
    exscan_deg<<<1, 256, 0, stream>>>(deg_i, offs, cursor, degf, N);
    fill_perm<<<eb, 256, 0, stream>>>(ei, cursor, perm, E);

    // ---- operand prep ----
    cvt_f32_bf16<<<1024, 256, 0, stream>>>(x, xb16, (long)N * KDIM / 4);
    pack_weights<<<256, 256, 0, stream>>>(lin_W, c1_Wl, c1_Wr, c2_Wl, c2_Wr, wp);

    // layer 1: h1 = relu(x @ lin_W^T + lin_b)
    gemm_mfma<8, false, 1><<<nb, 256, 0, stream>>>(
        xb16, nullptr, wp, nullptr, lin_b, h1, N);

    // conv1: agg = mean_{j->i} h1[j];  h2 = relu(agg @ Wl^T + b + h1 @ Wr^T)
    csr_gather_mean<<<gb, 256, 0, stream>>>(h1, offs, perm, degf, aggb, N);
    gemm_mfma<8, true, 1><<<nb, 256, 0, stream>>>(
        aggb, h1, wp + 16384, wp + 32768, c1_bl, h2, N);

    // conv2 + log_softmax
    csr_gather_mean<<<gb, 256, 0, stream>>>(h2, offs, perm, degf, aggb, N);
    gemm_mfma<4, true, 2><<<nb, 256, 0, stream>>>(
        aggb, h2, wp + 49152, wp + 57344, c2_bl, out, N);
}

// Round 4
// 396.119 us; speedup vs baseline: 14.5865x; 1.3464x over previous
//
#include <hip/hip_runtime.h>

// GraphSAGE forward: lin+relu -> SAGEConv(mean)+relu -> SAGEConv(mean) -> log_softmax
// N=100000, E=1.6M, dims 128 -> 128 -> 128 -> 64.
//
// Round 4: single-workgroup exscan (148us, 28% of total) replaced by 3-kernel
// hierarchical scan (block_reduce -> scan_bsums -> block_scan_apply, ~10us).
// GEMMs: bf16 MFMA 16x16x32 fp32-accum, pre-packed weight fragments,
// global_load_lds(16B) staging with XOR-swizzled source. Gather: CSR-by-dst.

#define KDIM 128

using bf16x8 = __attribute__((ext_vector_type(8))) short;
using f32x4  = __attribute__((ext_vector_type(4))) float;

__device__ __forceinline__ unsigned short f2bf_u(float f) {
    unsigned u = __float_as_uint(f);
    u += 0x7fffu + ((u >> 16) & 1u);
    return (unsigned short)(u >> 16);
}
__device__ __forceinline__ unsigned packbf2(float a, float b) {
    return (unsigned)f2bf_u(a) | ((unsigned)f2bf_u(b) << 16);
}
__device__ __forceinline__ float bflo(unsigned u) { return __uint_as_float(u << 16); }
__device__ __forceinline__ float bfhi(unsigned u) { return __uint_as_float(u & 0xffff0000u); }

__device__ __forceinline__ void gload_lds16(const short* g, short* l) {
    __builtin_amdgcn_global_load_lds(
        (const __attribute__((address_space(1))) unsigned int*)g,
        (__attribute__((address_space(3))) unsigned int*)l, 16, 0, 0);
}

__global__ void zero_i(int* __restrict__ p, int n) {
    int i = blockIdx.x * 256 + threadIdx.x;
    if (i < n) p[i] = 0;
}

__global__ __launch_bounds__(256) void compute_deg(
    const int* __restrict__ ei, int* __restrict__ deg_i, int E)
{
    int e = blockIdx.x * 256 + threadIdx.x;
    if (e < E) atomicAdd(&deg_i[ei[E + e]], 1);
}

// ---- hierarchical exclusive scan: 1024 elems/block ----
__global__ __launch_bounds__(256) void block_reduce(
    const int* __restrict__ deg_i, int* __restrict__ bsum, int n)
{
    const int t = threadIdx.x;
    const int idx = blockIdx.x * 1024 + t * 4;
    int s = 0;
    if (idx + 4 <= n) {
        int4 a = *(const int4*)(deg_i + idx);
        s = a.x + a.y + a.z + a.w;
    } else {
        #pragma unroll
        for (int k = 0; k < 4; ++k) if (idx + k < n) s += deg_i[idx + k];
    }
    #pragma unroll
    for (int d = 1; d < 64; d <<= 1) s += __shfl_xor(s, d);
    __shared__ int ws[4];
    if ((t & 63) == 0) ws[t >> 6] = s;
    __syncthreads();
    if (t == 0) bsum[blockIdx.x] = ws[0] + ws[1] + ws[2] + ws[3];
}

// single block: exclusive scan of bsum[0..nb) in place; bsum[nb] = total. nb < 256.
__global__ __launch_bounds__(256) void scan_bsums(int* __restrict__ bsum, int nb)
{
    const int t = threadIdx.x;
    const int lane = t & 63, wid = t >> 6;
    int v = (t < nb) ? bsum[t] : 0;
    int incl = v;
    #pragma unroll
    for (int d = 1; d < 64; d <<= 1) {
        int u = __shfl_up(incl, d);
        if (lane >= d) incl += u;
    }
    __shared__ int ws[4];
    if (lane == 63) ws[wid] = incl;
    __syncthreads();
    int woff = 0;
    #pragma unroll
    for (int w = 0; w < 4; ++w) if (w < wid) woff += ws[w];
    const int excl = woff + incl - v;
    if (t <= nb) bsum[t] = excl;   // t==nb: v=0 -> excl == grand total
}

__global__ __launch_bounds__(256) void block_scan_apply(
    const int* __restrict__ deg_i, const int* __restrict__ bsum,
    int* __restrict__ offs, int* __restrict__ cursor,
    float* __restrict__ degf, int n, int nb)
{
    const int t = threadIdx.x;
    const int lane = t & 63, wid = t >> 6;
    const int idx = blockIdx.x * 1024 + t * 4;
    int v[4] = {0, 0, 0, 0};
    if (idx + 4 <= n) {
        int4 a = *(const int4*)(deg_i + idx);
        v[0] = a.x; v[1] = a.y; v[2] = a.z; v[3] = a.w;
    } else {
        #pragma unroll
        for (int k = 0; k < 4; ++k) if (idx + k < n) v[k] = deg_i[idx + k];
    }
    const int sum = v[0] + v[1] + v[2] + v[3];
    int incl = sum;
    #pragma unroll
    for (int d = 1; d < 64; d <<= 1) {
        int u = __shfl_up(incl, d);
        if (lane >= d) incl += u;
    }
    __shared__ int ws[4];
    if (lane == 63) ws[wid] = incl;
    __syncthreads();
    int woff = 0;
    #pragma unroll
    for (int w = 0; w < 4; ++w) if (w < wid) woff += ws[w];
    int excl = bsum[blockIdx.x] + woff + (incl - sum);
    #pragma unroll
    for (int k = 0; k < 4; ++k) {
        if (idx + k < n) {
            offs[idx + k] = excl;
            cursor[idx + k] = excl;
            degf[idx + k] = (float)v[k];
            excl += v[k];
        }
    }
    if (blockIdx.x == 0 && t == 0) offs[n] = bsum[nb];
}

__global__ __launch_bounds__(256) void fill_perm(
    const int* __restrict__ ei, int* __restrict__ cursor,
    int* __restrict__ perm, int E)
{
    int e = blockIdx.x * 256 + threadIdx.x;
    if (e >= E) return;
    int src = ei[e];
    int dst = ei[E + e];
    int pos = atomicAdd(&cursor[dst], 1);
    perm[pos] = src;
}

__global__ __launch_bounds__(256) void cvt_f32_bf16(
    const float* __restrict__ x, short* __restrict__ y, long n4)
{
    long i = (long)blockIdx.x * 256 + threadIdx.x;
    long stride = (long)gridDim.x * 256;
    const float4* x4 = (const float4*)x;
    for (long j = i; j < n4; j += stride) {
        float4 v = x4[j];
        uint2 o;
        o.x = packbf2(v.x, v.y);
        o.y = packbf2(v.z, v.w);
        *(uint2*)(y + j * 4) = o;
    }
}

// Pack 5 weight matrices into MFMA B-fragment layout:
// wp[ks][cf][lane][j] = bf16(W[cf*16 + (lane&15)][ks*32 + (lane>>4)*8 + j])
__global__ __launch_bounds__(256) void pack_weights(
    const float* __restrict__ Wlin, const float* __restrict__ Wc1l,
    const float* __restrict__ Wc1r, const float* __restrict__ Wc2l,
    const float* __restrict__ Wc2r, short* __restrict__ wp)
{
    int idx = blockIdx.x * 256 + threadIdx.x;   // 0..65535
    if (idx >= 65536) return;
    const float* W; short* dst; int off, ncf;
    if (idx < 16384)      { W = Wlin; dst = wp;         off = idx;         ncf = 8; }
    else if (idx < 32768) { W = Wc1l; dst = wp + 16384; off = idx - 16384; ncf = 8; }
    else if (idx < 49152) { W = Wc1r; dst = wp + 32768; off = idx - 32768; ncf = 8; }
    else if (idx < 57344) { W = Wc2l; dst = wp + 49152; off = idx - 49152; ncf = 4; }
    else                  { W = Wc2r; dst = wp + 57344; off = idx - 57344; ncf = 4; }
    int j    = off & 7;
    int lane = (off >> 3) & 63;
    int cf   = (off >> 9) & (ncf - 1);
    int ks   = off >> ((ncf == 8) ? 12 : 11);
    int m = cf * 16 + (lane & 15);
    int k = ks * 32 + ((lane >> 4) << 3) + j;
    dst[off] = (short)f2bf_u(W[m * KDIM + k]);
}

// 2 nodes per wave (32 lanes/node, 8B per lane): agg[n] = bf16(sum_{j} h[j] / max(deg,1))
__global__ __launch_bounds__(256) void csr_gather_mean(
    const short* __restrict__ h, const int* __restrict__ offs,
    const int* __restrict__ perm, const float* __restrict__ degf,
    short* __restrict__ agg, int N)
{
    const int node = blockIdx.x * 8 + (threadIdx.x >> 5);
    if (node >= N) return;
    const int hl = threadIdx.x & 31;
    const int b = offs[node], e = offs[node + 1];
    float a0 = 0.f, a1 = 0.f, a2 = 0.f, a3 = 0.f;
    float b0 = 0.f, b1 = 0.f, b2 = 0.f, b3 = 0.f;
    int i = b;
    for (; i + 2 <= e; i += 2) {
        const int s0 = perm[i], s1 = perm[i + 1];
        const uint2 u = *(const uint2*)(h + (long)s0 * KDIM + hl * 4);
        const uint2 v = *(const uint2*)(h + (long)s1 * KDIM + hl * 4);
        a0 += bflo(u.x); a1 += bfhi(u.x); a2 += bflo(u.y); a3 += bfhi(u.y);
        b0 += bflo(v.x); b1 += bfhi(v.x); b2 += bflo(v.y); b3 += bfhi(v.y);
    }
    if (i < e) {
        const uint2 u = *(const uint2*)(h + (long)perm[i] * KDIM + hl * 4);
        a0 += bflo(u.x); a1 += bfhi(u.x); a2 += bflo(u.y); a3 += bfhi(u.y);
    }
    const float inv = 1.f / fmaxf(degf[node], 1.f);
    uint2 o;
    o.x = packbf2((a0 + b0) * inv, (a1 + b1) * inv);
    o.y = packbf2((a2 + b2) * inv, (a3 + b3) * inv);
    *(uint2*)(agg + (long)node * KDIM + hl * 4) = o;
}

// out = act( A @ WA^T + bias [+ B @ WB^T] ).  A,B bf16 row-major [N][128].
// Weights pre-packed in fragment layout. 64-row tile/block, 4 waves.
// NCF=8 (out 128 cols): wave w -> col-frags {2w,2w+1}, row-frags 0..3.
// NCF=4 (out  64 cols): wave w -> row-frag w, col-frags 0..3.
// ACT: 1 relu -> bf16 out; 2 log_softmax -> f32 out.
template<int NCF, bool HAS_B, int ACT>
__global__ __launch_bounds__(256) void gemm_mfma(
    const short* __restrict__ A, const short* __restrict__ B,
    const short* __restrict__ wpA, const short* __restrict__ wpB,
    const float* __restrict__ bias, void* __restrict__ outp, int N)
{
    constexpr int CFW = (NCF == 8) ? 2 : 4;
    constexpr int RFW = (NCF == 8) ? 4 : 1;
    __shared__ __attribute__((aligned(16))) short xa[64 * KDIM];
    __shared__ __attribute__((aligned(16))) short xb[HAS_B ? 64 * KDIM : 8];

    const int t = threadIdx.x;
    const int w = t >> 6, lane = t & 63;
    const int row0 = blockIdx.x * 64;
    const int cf0 = (NCF == 8) ? w * 2 : 0;
    const int rf0 = (NCF == 8) ? 0 : w;

    // ---- weight B-fragments -> registers (coalesced 16B/lane) ----
    bf16x8 bwA[4][CFW];
    bf16x8 bwB[HAS_B ? 4 : 1][HAS_B ? CFW : 1];
    #pragma unroll
    for (int ks = 0; ks < 4; ++ks)
        #pragma unroll
        for (int c = 0; c < CFW; ++c) {
            bwA[ks][c] = *(const bf16x8*)(wpA + (((ks * NCF) + cf0 + c) * 64 + lane) * 8);
            if (HAS_B)
                bwB[ks][c] = *(const bf16x8*)(wpB + (((ks * NCF) + cf0 + c) * 64 + lane) * 8);
        }

    // ---- stage A (and B) 64x128 tiles: global_load_lds, XOR-swizzled source ----
    // LDS granule (row, s) holds global granule (s ^ (row&7)); granule = 8 bf16 = 16B.
    #pragma unroll
    for (int ii = 0; ii < 4; ++ii) {
        const int i = w * 4 + ii;
        const int rl = i * 4 + (lane >> 4);
        const int grow = min(row0 + rl, N - 1);
        const int gs = (lane & 15) ^ (rl & 7);
        gload_lds16(A + (long)grow * KDIM + gs * 8, &xa[i * 512]);
        if (HAS_B) gload_lds16(B + (long)grow * KDIM + gs * 8, &xb[i * 512]);
    }

    // ---- accumulators init with bias (col = (cf0+c)*16 + (lane&15)) ----
    f32x4 acc[RFW][CFW];
    #pragma unroll
    for (int c = 0; c < CFW; ++c) {
        const float bv = bias[(cf0 + c) * 16 + (lane & 15)];
        #pragma unroll
        for (int rf = 0; rf < RFW; ++rf)
            acc[rf][c] = f32x4{bv, bv, bv, bv};
    }

    __syncthreads();   // drains global_load_lds (vmcnt) + barrier

    // ---- MFMA: K = 4 steps of 32 ----
    #pragma unroll
    for (int ks = 0; ks < 4; ++ks) {
        #pragma unroll
        for (int rf = 0; rf < RFW; ++rf) {
            const int rl = (rf0 + rf) * 16 + (lane & 15);
            const int s = (ks * 4 + (lane >> 4)) ^ (rl & 7);
            const bf16x8 a = *(const bf16x8*)(xa + rl * KDIM + s * 8);
            #pragma unroll
            for (int c = 0; c < CFW; ++c)
                acc[rf][c] = __builtin_amdgcn_mfma_f32_16x16x32_bf16(
                    a, bwA[ks][c], acc[rf][c], 0, 0, 0);
            if (HAS_B) {
                const bf16x8 bb = *(const bf16x8*)(xb + rl * KDIM + s * 8);
                #pragma unroll
                for (int c = 0; c < CFW; ++c)
                    acc[rf][c] = __builtin_amdgcn_mfma_f32_16x16x32_bf16(
                        bb, bwB[ks][c], acc[rf][c], 0, 0, 0);
            }
        }
    }

    // ---- epilogue ----
    // C/D layout: col = lane&15, row = (lane>>4)*4 + reg  [m89-verified]
    if (ACT != 2) {
        short* out = (short*)outp;
        #pragma unroll
        for (int rf = 0; rf < RFW; ++rf)
            #pragma unroll
            for (int c = 0; c < CFW; ++c)
                #pragma unroll
                for (int q = 0; q < 4; ++q) {
                    const int row = row0 + (rf0 + rf) * 16 + (lane >> 4) * 4 + q;
                    if (row < N) {
                        float v = acc[rf][c][q];
                        if (ACT == 1) v = fmaxf(v, 0.f);
                        out[(long)row * (NCF * 16) + (cf0 + c) * 16 + (lane & 15)] =
                            (short)f2bf_u(v);
                    }
                }
    } else {
        // NCF==4: RFW=1; lane holds cols {c*16 + (lane&15)}, rows w*16 + (lane>>4)*4 + q
        float* out = (float*)outp;
        #pragma unroll
        for (int q = 0; q < 4; ++q) {
            float m = fmaxf(fmaxf(acc[0][0][q], acc[0][1][q]),
                            fmaxf(acc[0][2][q], acc[0][3][q]));
            #pragma unroll
            for (int mk = 1; mk < 16; mk <<= 1) m = fmaxf(m, __shfl_xor(m, mk));
            float s = 0.f;
            #pragma unroll
            for (int c = 0; c < 4; ++c) s += expf(acc[0][c][q] - m);
            #pragma unroll
            for (int mk = 1; mk < 16; mk <<= 1) s += __shfl_xor(s, mk);
            const float L = m + logf(s);
            const int row = row0 + rf0 * 16 + (lane >> 4) * 4 + q;
            if (row < N) {
                #pragma unroll
                for (int c = 0; c < 4; ++c)
                    out[(long)row * 64 + c * 16 + (lane & 15)] = acc[0][c][q] - L;
            }
        }
    }
}

extern "C" void kernel_launch(void* const* d_in, const int* in_sizes, int n_in,
                              void* d_out, int out_size, void* d_ws, size_t ws_size,
                              hipStream_t stream) {
    const float* x     = (const float*)d_in[0];
    const int*   ei    = (const int*)d_in[1];
    const float* lin_W = (const float*)d_in[2];
    const float* lin_b = (const float*)d_in[3];
    const float* c1_Wl = (const float*)d_in[4];
    const float* c1_bl = (const float*)d_in[5];
    const float* c1_Wr = (const float*)d_in[6];
    const float* c2_Wl = (const float*)d_in[7];
    const float* c2_bl = (const float*)d_in[8];
    const float* c2_Wr = (const float*)d_in[9];
    float* out = (float*)d_out;

    const int N = in_sizes[0] / KDIM;
    const int E = in_sizes[1] / 2;

    short* xb16 = (short*)d_ws;                  // N*128 bf16
    short* h1   = xb16 + (size_t)N * KDIM;       // N*128 bf16
    short* h2   = h1 + (size_t)N * KDIM;         // N*128 bf16
    short* aggb = h2 + (size_t)N * KDIM;         // N*128 bf16
    short* wp   = aggb + (size_t)N * KDIM;       // 65536 bf16 (packed weights)
    float* degf = (float*)(wp + 65536);          // N f32
    int* offs   = (int*)(degf + N);              // N+1
    int* cursor = offs + (N + 1);                // N
    int* deg_i  = cursor + N;                    // N
    int* bsum   = deg_i + N;                     // nsb+1
    int* perm   = bsum + 1024;                   // E

    const int eb = (E + 255) / 256;
    const int nb = (N + 63) / 64;
    const int gb = (N + 7) / 8;
    const int nsb = (N + 1023) / 1024;           // scan blocks (98 < 256)

    // ---- CSR build (graph shared by both convs) ----
    zero_i<<<(N + 255) / 256, 256, 0, stream>>>(deg_i, N);
    compute_deg<<<eb, 256, 0, stream>>>(ei, deg_i, E);
    block_reduce<<<nsb, 256, 0, stream>>>(deg_i, bsum, N);
    scan_bsums<<<1, 256, 0, stream>>>(bsum, nsb);
    block_scan_apply<<<nsb, 256, 0, stream>>>(deg_i, bsum, offs, cursor, degf, N, nsb);
    fill_perm<<<eb, 256, 0, stream>>>(ei, cursor, perm, E);

    // ---- operand prep ----
    cvt_f32_bf16<<<1024, 256, 0, stream>>>(x, xb16, (long)N * KDIM / 4);
    pack_weights<<<256, 256, 0, stream>>>(lin_W, c1_Wl, c1_Wr, c2_Wl, c2_Wr, wp);

    // layer 1: h1 = relu(x @ lin_W^T + lin_b)
    gemm_mfma<8, false, 1><<<nb, 256, 0, stream>>>(
        xb16, nullptr, wp, nullptr, lin_b, h1, N);

    // conv1: agg = mean_{j->i} h1[j];  h2 = relu(agg @ Wl^T + b + h1 @ Wr^T)
    csr_gather_mean<<<gb, 256, 0, stream>>>(h1, offs, perm, degf, aggb, N);
    gemm_mfma<8, true, 1><<<nb, 256, 0, stream>>>(
        aggb, h1, wp + 16384, wp + 32768, c1_bl, h2, N);

    // conv2 + log_softmax
    csr_gather_mean<<<gb, 256, 0, stream>>>(h2, offs, perm, degf, aggb, N);
    gemm_mfma<4, true, 2><<<nb, 256, 0, stream>>>(
        aggb, h2, wp + 49152, wp + 57344, c2_bl, out, N);
}

// Round 5
// 264.976 us; speedup vs baseline: 21.8057x; 1.4949x over previous
//
#include <hip/hip_runtime.h>

// GraphSAGE forward: lin+relu -> SAGEConv(mean)+relu -> SAGEConv(mean) -> log_softmax
// N=100000, E=1.6M, dims 128 -> 128 -> 128 -> 64.
//
// Round 5: CSR build rewritten as two-level multisplit counting sort
// (bin_hist -> scan -> bin_scatter -> bucket_sort). No global atomics, all
// writes region-sequential; replaces fill_perm (130us, 105MB line-RMW traffic)
// + compute_deg + N-scan. GEMMs: bf16 MFMA; gather: CSR; unchanged.

#define KDIM 128
#define CH 16384            // edges per multisplit chunk
#define BSH 8               // bucket shift: bucket = dst >> 8 (256 nodes/bucket)
#define BCAP 8192           // per-bucket LDS capacity (avg ~4100, sd ~64)

using bf16x8 = __attribute__((ext_vector_type(8))) short;
using f32x4  = __attribute__((ext_vector_type(4))) float;

__device__ __forceinline__ unsigned short f2bf_u(float f) {
    unsigned u = __float_as_uint(f);
    u += 0x7fffu + ((u >> 16) & 1u);
    return (unsigned short)(u >> 16);
}
__device__ __forceinline__ unsigned packbf2(float a, float b) {
    return (unsigned)f2bf_u(a) | ((unsigned)f2bf_u(b) << 16);
}
__device__ __forceinline__ float bflo(unsigned u) { return __uint_as_float(u << 16); }
__device__ __forceinline__ float bfhi(unsigned u) { return __uint_as_float(u & 0xffff0000u); }

__device__ __forceinline__ void gload_lds16(const short* g, short* l) {
    __builtin_amdgcn_global_load_lds(
        (const __attribute__((address_space(1))) unsigned int*)g,
        (__attribute__((address_space(3))) unsigned int*)l, 16, 0, 0);
}

// ---- multisplit CSR build ----

__global__ __launch_bounds__(256) void bin_hist(
    const int* __restrict__ ei, int* __restrict__ hist, int E, int nwg, int NB)
{
    __shared__ int lh[512];
    const int w = blockIdx.x, t = threadIdx.x;
    for (int b = t; b < NB; b += 256) lh[b] = 0;
    __syncthreads();
    const int e0 = w * CH, e1 = min(E, e0 + CH);
    for (int e = e0 + t; e < e1; e += 256)
        atomicAdd(&lh[ei[E + e] >> BSH], 1);
    __syncthreads();
    for (int b = t; b < NB; b += 256) hist[b * nwg + w] = lh[b];
}

// reduce 1024 ints/block -> bsum[block]
__global__ __launch_bounds__(256) void greduce(
    const int* __restrict__ in, int* __restrict__ bsum, int n)
{
    const int t = threadIdx.x;
    const int idx = blockIdx.x * 1024 + t * 4;
    int s = 0;
    if (idx + 4 <= n) {
        int4 a = *(const int4*)(in + idx);
        s = a.x + a.y + a.z + a.w;
    } else {
        #pragma unroll
        for (int k = 0; k < 4; ++k) if (idx + k < n) s += in[idx + k];
    }
    #pragma unroll
    for (int d = 1; d < 64; d <<= 1) s += __shfl_xor(s, d);
    __shared__ int ws[4];
    if ((t & 63) == 0) ws[t >> 6] = s;
    __syncthreads();
    if (t == 0) bsum[blockIdx.x] = ws[0] + ws[1] + ws[2] + ws[3];
}

// single block: exclusive scan bsum[0..nb) in place; bsum[nb] = total (nb < 256)
__global__ __launch_bounds__(256) void scan_bsums(int* __restrict__ bsum, int nb)
{
    const int t = threadIdx.x;
    const int lane = t & 63, wid = t >> 6;
    int v = (t < nb) ? bsum[t] : 0;
    int incl = v;
    #pragma unroll
    for (int d = 1; d < 64; d <<= 1) {
        int u = __shfl_up(incl, d);
        if (lane >= d) incl += u;
    }
    __shared__ int ws[4];
    if (lane == 63) ws[wid] = incl;
    __syncthreads();
    int woff = 0;
    #pragma unroll
    for (int w = 0; w < 4; ++w) if (w < wid) woff += ws[w];
    const int excl = woff + incl - v;
    if (t <= nb) bsum[t] = excl;
}

// in-place exclusive scan of io[0..n) given per-1024-block exclusive bases
__global__ __launch_bounds__(256) void gapply(
    int* __restrict__ io, const int* __restrict__ bsum, int n)
{
    const int t = threadIdx.x;
    const int lane = t & 63, wid = t >> 6;
    const int idx = blockIdx.x * 1024 + t * 4;
    int v[4] = {0, 0, 0, 0};
    if (idx + 4 <= n) {
        int4 a = *(const int4*)(io + idx);
        v[0] = a.x; v[1] = a.y; v[2] = a.z; v[3] = a.w;
    } else {
        #pragma unroll
        for (int k = 0; k < 4; ++k) if (idx + k < n) v[k] = io[idx + k];
    }
    const int sum = v[0] + v[1] + v[2] + v[3];
    int incl = sum;
    #pragma unroll
    for (int d = 1; d < 64; d <<= 1) {
        int u = __shfl_up(incl, d);
        if (lane >= d) incl += u;
    }
    __shared__ int ws[4];
    if (lane == 63) ws[wid] = incl;
    __syncthreads();
    int woff = 0;
    #pragma unroll
    for (int w = 0; w < 4; ++w) if (w < wid) woff += ws[w];
    int excl = bsum[blockIdx.x] + woff + (incl - sum);
    if (idx + 4 <= n) {
        int4 o;
        o.x = excl; o.y = excl + v[0]; o.z = excl + v[0] + v[1];
        o.w = excl + v[0] + v[1] + v[2];
        *(int4*)(io + idx) = o;
    } else {
        #pragma unroll
        for (int k = 0; k < 4; ++k) {
            if (idx + k < n) { io[idx + k] = excl; excl += v[k]; }
        }
    }
}

// scatter packed edges into per-(bucket, wg) private regions (LDS cursors)
__global__ __launch_bounds__(256) void bin_scatter(
    const int* __restrict__ ei, const int* __restrict__ hist_s,
    unsigned* __restrict__ packed, int E, int nwg, int NB)
{
    __shared__ int lc[512];
    const int w = blockIdx.x, t = threadIdx.x;
    for (int b = t; b < NB; b += 256) lc[b] = hist_s[b * nwg + w];
    __syncthreads();
    const int e0 = w * CH, e1 = min(E, e0 + CH);
    for (int e = e0 + t; e < e1; e += 256) {
        const int src = ei[e];
        const int dst = ei[E + e];
        const int b = dst >> BSH;
        const int pos = atomicAdd(&lc[b], 1);
        packed[pos] = ((unsigned)(dst & 255) << 17) | (unsigned)src;
    }
}

// one wg per bucket: LDS counting sort -> perm (coalesced), offs, degf
__global__ __launch_bounds__(256) void bucket_sort(
    const unsigned* __restrict__ packed, const int* __restrict__ hist_s,
    int* __restrict__ offs, float* __restrict__ degf, int* __restrict__ perm,
    int E, int nwg, int NB, int N)
{
    __shared__ unsigned le[BCAP];
    __shared__ int lp[BCAP];
    __shared__ int lh[256], lx[256], lc[256];
    __shared__ int ws[4];
    const int b = blockIdx.x, t = threadIdx.x;
    const int bb = hist_s[b * nwg];
    const int be = (b + 1 < NB) ? hist_s[(b + 1) * nwg] : E;
    int cnt = be - bb;
    if (cnt > BCAP) cnt = BCAP;   // safety; statistically unreachable
    for (int i = t; i < cnt; i += 256) le[i] = packed[bb + i];
    lh[t] = 0;
    __syncthreads();
    for (int i = t; i < cnt; i += 256) atomicAdd(&lh[le[i] >> 17], 1);
    __syncthreads();
    // exclusive scan of lh[256]
    const int lane = t & 63, wid = t >> 6;
    const int v = lh[t];
    int incl = v;
    #pragma unroll
    for (int d = 1; d < 64; d <<= 1) {
        int u = __shfl_up(incl, d);
        if (lane >= d) incl += u;
    }
    if (lane == 63) ws[wid] = incl;
    __syncthreads();
    int woff = 0;
    #pragma unroll
    for (int w = 0; w < 4; ++w) if (w < wid) woff += ws[w];
    const int excl = woff + incl - v;
    lx[t] = excl;
    lc[t] = excl;
    __syncthreads();
    for (int i = t; i < cnt; i += 256) {
        const unsigned p = le[i];
        const int pos = atomicAdd(&lc[p >> 17], 1);
        lp[pos] = (int)(p & 0x1FFFFu);
    }
    __syncthreads();
    for (int i = t; i < cnt; i += 256) perm[bb + i] = lp[i];
    const int node = (b << BSH) + t;
    if (node < N) {
        offs[node] = bb + lx[t];
        degf[node] = (float)v;
    }
    if (b == NB - 1 && t == 0) offs[N] = E;
}

// ---- operand prep ----

__global__ __launch_bounds__(256) void cvt_f32_bf16(
    const float* __restrict__ x, short* __restrict__ y, long n4)
{
    long i = (long)blockIdx.x * 256 + threadIdx.x;
    long stride = (long)gridDim.x * 256;
    const float4* x4 = (const float4*)x;
    for (long j = i; j < n4; j += stride) {
        float4 v = x4[j];
        uint2 o;
        o.x = packbf2(v.x, v.y);
        o.y = packbf2(v.z, v.w);
        *(uint2*)(y + j * 4) = o;
    }
}

// Pack 5 weight matrices into MFMA B-fragment layout:
// wp[ks][cf][lane][j] = bf16(W[cf*16 + (lane&15)][ks*32 + (lane>>4)*8 + j])
__global__ __launch_bounds__(256) void pack_weights(
    const float* __restrict__ Wlin, const float* __restrict__ Wc1l,
    const float* __restrict__ Wc1r, const float* __restrict__ Wc2l,
    const float* __restrict__ Wc2r, short* __restrict__ wp)
{
    int idx = blockIdx.x * 256 + threadIdx.x;   // 0..65535
    if (idx >= 65536) return;
    const float* W; short* dst; int off, ncf;
    if (idx < 16384)      { W = Wlin; dst = wp;         off = idx;         ncf = 8; }
    else if (idx < 32768) { W = Wc1l; dst = wp + 16384; off = idx - 16384; ncf = 8; }
    else if (idx < 49152) { W = Wc1r; dst = wp + 32768; off = idx - 32768; ncf = 8; }
    else if (idx < 57344) { W = Wc2l; dst = wp + 49152; off = idx - 49152; ncf = 4; }
    else                  { W = Wc2r; dst = wp + 57344; off = idx - 57344; ncf = 4; }
    int j    = off & 7;
    int lane = (off >> 3) & 63;
    int cf   = (off >> 9) & (ncf - 1);
    int ks   = off >> ((ncf == 8) ? 12 : 11);
    int m = cf * 16 + (lane & 15);
    int k = ks * 32 + ((lane >> 4) << 3) + j;
    dst[off] = (short)f2bf_u(W[m * KDIM + k]);
}

// 2 nodes per wave (32 lanes/node, 8B/lane): agg[n] = bf16(sum_j h[j] / max(deg,1))
__global__ __launch_bounds__(256) void csr_gather_mean(
    const short* __restrict__ h, const int* __restrict__ offs,
    const int* __restrict__ perm, const float* __restrict__ degf,
    short* __restrict__ agg, int N)
{
    const int node = blockIdx.x * 8 + (threadIdx.x >> 5);
    if (node >= N) return;
    const int hl = threadIdx.x & 31;
    const int b = offs[node], e = offs[node + 1];
    float a0 = 0.f, a1 = 0.f, a2 = 0.f, a3 = 0.f;
    float b0 = 0.f, b1 = 0.f, b2 = 0.f, b3 = 0.f;
    int i = b;
    for (; i + 2 <= e; i += 2) {
        const int s0 = perm[i], s1 = perm[i + 1];
        const uint2 u = *(const uint2*)(h + (long)s0 * KDIM + hl * 4);
        const uint2 v = *(const uint2*)(h + (long)s1 * KDIM + hl * 4);
        a0 += bflo(u.x); a1 += bfhi(u.x); a2 += bflo(u.y); a3 += bfhi(u.y);
        b0 += bflo(v.x); b1 += bfhi(v.x); b2 += bflo(v.y); b3 += bfhi(v.y);
    }
    if (i < e) {
        const uint2 u = *(const uint2*)(h + (long)perm[i] * KDIM + hl * 4);
        a0 += bflo(u.x); a1 += bfhi(u.x); a2 += bflo(u.y); a3 += bfhi(u.y);
    }
    const float inv = 1.f / fmaxf(degf[node], 1.f);
    uint2 o;
    o.x = packbf2((a0 + b0) * inv, (a1 + b1) * inv);
    o.y = packbf2((a2 + b2) * inv, (a3 + b3) * inv);
    *(uint2*)(agg + (long)node * KDIM + hl * 4) = o;
}

// out = act( A @ WA^T + bias [+ B @ WB^T] ).  A,B bf16 row-major [N][128].
// Weights pre-packed in fragment layout. 64-row tile/block, 4 waves.
// NCF=8: wave w -> col-frags {2w,2w+1}, row-frags 0..3.
// NCF=4: wave w -> row-frag w, col-frags 0..3.
// ACT: 1 relu -> bf16 out; 2 log_softmax -> f32 out.
template<int NCF, bool HAS_B, int ACT>
__global__ __launch_bounds__(256) void gemm_mfma(
    const short* __restrict__ A, const short* __restrict__ B,
    const short* __restrict__ wpA, const short* __restrict__ wpB,
    const float* __restrict__ bias, void* __restrict__ outp, int N)
{
    constexpr int CFW = (NCF == 8) ? 2 : 4;
    constexpr int RFW = (NCF == 8) ? 4 : 1;
    __shared__ __attribute__((aligned(16))) short xa[64 * KDIM];
    __shared__ __attribute__((aligned(16))) short xb[HAS_B ? 64 * KDIM : 8];

    const int t = threadIdx.x;
    const int w = t >> 6, lane = t & 63;
    const int row0 = blockIdx.x * 64;
    const int cf0 = (NCF == 8) ? w * 2 : 0;
    const int rf0 = (NCF == 8) ? 0 : w;

    // weight B-fragments -> registers (coalesced 16B/lane)
    bf16x8 bwA[4][CFW];
    bf16x8 bwB[HAS_B ? 4 : 1][HAS_B ? CFW : 1];
    #pragma unroll
    for (int ks = 0; ks < 4; ++ks)
        #pragma unroll
        for (int c = 0; c < CFW; ++c) {
            bwA[ks][c] = *(const bf16x8*)(wpA + (((ks * NCF) + cf0 + c) * 64 + lane) * 8);
            if (HAS_B)
                bwB[ks][c] = *(const bf16x8*)(wpB + (((ks * NCF) + cf0 + c) * 64 + lane) * 8);
        }

    // stage A (and B) 64x128 tiles: global_load_lds, XOR-swizzled source
    #pragma unroll
    for (int ii = 0; ii < 4; ++ii) {
        const int i = w * 4 + ii;
        const int rl = i * 4 + (lane >> 4);
        const int grow = min(row0 + rl, N - 1);
        const int gs = (lane & 15) ^ (rl & 7);
        gload_lds16(A + (long)grow * KDIM + gs * 8, &xa[i * 512]);
        if (HAS_B) gload_lds16(B + (long)grow * KDIM + gs * 8, &xb[i * 512]);
    }

    // accumulators init with bias (col = (cf0+c)*16 + (lane&15))
    f32x4 acc[RFW][CFW];
    #pragma unroll
    for (int c = 0; c < CFW; ++c) {
        const float bv = bias[(cf0 + c) * 16 + (lane & 15)];
        #pragma unroll
        for (int rf = 0; rf < RFW; ++rf)
            acc[rf][c] = f32x4{bv, bv, bv, bv};
    }

    __syncthreads();   // drains global_load_lds (vmcnt) + barrier

    // MFMA: K = 4 steps of 32
    #pragma unroll
    for (int ks = 0; ks < 4; ++ks) {
        #pragma unroll
        for (int rf = 0; rf < RFW; ++rf) {
            const int rl = (rf0 + rf) * 16 + (lane & 15);
            const int s = (ks * 4 + (lane >> 4)) ^ (rl & 7);
            const bf16x8 a = *(const bf16x8*)(xa + rl * KDIM + s * 8);
            #pragma unroll
            for (int c = 0; c < CFW; ++c)
                acc[rf][c] = __builtin_amdgcn_mfma_f32_16x16x32_bf16(
                    a, bwA[ks][c], acc[rf][c], 0, 0, 0);
            if (HAS_B) {
                const bf16x8 bb = *(const bf16x8*)(xb + rl * KDIM + s * 8);
                #pragma unroll
                for (int c = 0; c < CFW; ++c)
                    acc[rf][c] = __builtin_amdgcn_mfma_f32_16x16x32_bf16(
                        bb, bwB[ks][c], acc[rf][c], 0, 0, 0);
            }
        }
    }

    // epilogue; C/D layout: col = lane&15, row = (lane>>4)*4 + reg
    if (ACT != 2) {
        short* out = (short*)outp;
        #pragma unroll
        for (int rf = 0; rf < RFW; ++rf)
            #pragma unroll
            for (int c = 0; c < CFW; ++c)
                #pragma unroll
                for (int q = 0; q < 4; ++q) {
                    const int row = row0 + (rf0 + rf) * 16 + (lane >> 4) * 4 + q;
                    if (row < N) {
                        float v = acc[rf][c][q];
                        if (ACT == 1) v = fmaxf(v, 0.f);
                        out[(long)row * (NCF * 16) + (cf0 + c) * 16 + (lane & 15)] =
                            (short)f2bf_u(v);
                    }
                }
    } else {
        float* out = (float*)outp;
        #pragma unroll
        for (int q = 0; q < 4; ++q) {
            float m = fmaxf(fmaxf(acc[0][0][q], acc[0][1][q]),
                            fmaxf(acc[0][2][q], acc[0][3][q]));
            #pragma unroll
            for (int mk = 1; mk < 16; mk <<= 1) m = fmaxf(m, __shfl_xor(m, mk));
            float s = 0.f;
            #pragma unroll
            for (int c = 0; c < 4; ++c) s += expf(acc[0][c][q] - m);
            #pragma unroll
            for (int mk = 1; mk < 16; mk <<= 1) s += __shfl_xor(s, mk);
            const float L = m + logf(s);
            const int row = row0 + rf0 * 16 + (lane >> 4) * 4 + q;
            if (row < N) {
                #pragma unroll
                for (int c = 0; c < 4; ++c)
                    out[(long)row * 64 + c * 16 + (lane & 15)] = acc[0][c][q] - L;
            }
        }
    }
}

extern "C" void kernel_launch(void* const* d_in, const int* in_sizes, int n_in,
                              void* d_out, int out_size, void* d_ws, size_t ws_size,
                              hipStream_t stream) {
    const float* x     = (const float*)d_in[0];
    const int*   ei    = (const int*)d_in[1];
    const float* lin_W = (const float*)d_in[2];
    const float* lin_b = (const float*)d_in[3];
    const float* c1_Wl = (const float*)d_in[4];
    const float* c1_bl = (const float*)d_in[5];
    const float* c1_Wr = (const float*)d_in[6];
    const float* c2_Wl = (const float*)d_in[7];
    const float* c2_bl = (const float*)d_in[8];
    const float* c2_Wr = (const float*)d_in[9];
    float* out = (float*)d_out;

    const int N = in_sizes[0] / KDIM;
    const int E = in_sizes[1] / 2;

    short* xb16 = (short*)d_ws;                  // N*128 bf16
    short* h1   = xb16 + (size_t)N * KDIM;       // N*128 bf16
    short* h2   = h1 + (size_t)N * KDIM;         // N*128 bf16
    short* aggb = h2 + (size_t)N * KDIM;         // N*128 bf16
    short* wp   = aggb + (size_t)N * KDIM;       // 65536 bf16 (packed weights)
    float* degf = (float*)(wp + 65536);          // N f32
    int* offs   = (int*)(degf + N);              // N+1
    const int nwg = (E + CH - 1) / CH;           // 98
    const int NB  = (N + 255) >> BSH;            // 391
    int* hist   = offs + (N + 1);                // NB*nwg
    int* bsum   = hist + NB * nwg;               // 256
    unsigned* packed = (unsigned*)(bsum + 256);  // E
    int* perm   = (int*)(packed + E);            // E

    const int nb = (N + 63) / 64;
    const int gb = (N + 7) / 8;
    const int nh = NB * nwg;
    const int nsb = (nh + 1023) / 1024;          // scan blocks (38 < 256)

    // ---- CSR build: two-level multisplit (no global atomics) ----
    bin_hist<<<nwg, 256, 0, stream>>>(ei, hist, E, nwg, NB);
    greduce<<<nsb, 256, 0, stream>>>(hist, bsum, nh);
    scan_bsums<<<1, 256, 0, stream>>>(bsum, nsb);
    gapply<<<nsb, 256, 0, stream>>>(hist, bsum, nh);
    bin_scatter<<<nwg, 256, 0, stream>>>(ei, hist, packed, E, nwg, NB);
    bucket_sort<<<NB, 256, 0, stream>>>(packed, hist, offs, degf, perm, E, nwg, NB, N);

    // ---- operand prep ----
    cvt_f32_bf16<<<1024, 256, 0, stream>>>(x, xb16, (long)N * KDIM / 4);
    pack_weights<<<256, 256, 0, stream>>>(lin_W, c1_Wl, c1_Wr, c2_Wl, c2_Wr, wp);

    // layer 1: h1 = relu(x @ lin_W^T + lin_b)
    gemm_mfma<8, false, 1><<<nb, 256, 0, stream>>>(
        xb16, nullptr, wp, nullptr, lin_b, h1, N);

    // conv1: agg = mean_{j->i} h1[j];  h2 = relu(agg @ Wl^T + b + h1 @ Wr^T)
    csr_gather_mean<<<gb, 256, 0, stream>>>(h1, offs, perm, degf, aggb, N);
    gemm_mfma<8, true, 1><<<nb, 256, 0, stream>>>(
        aggb, h1, wp + 16384, wp + 32768, c1_bl, h2, N);

    // conv2 + log_softmax
    csr_gather_mean<<<gb, 256, 0, stream>>>(h2, offs, perm, degf, aggb, N);
    gemm_mfma<4, true, 2><<<nb, 256, 0, stream>>>(
        aggb, h2, wp + 49152, wp + 57344, c2_bl, out, N);
}

// Round 6
// 239.673 us; speedup vs baseline: 24.1078x; 1.1056x over previous
//
#include <hip/hip_runtime.h>

// GraphSAGE forward: lin+relu -> SAGEConv(mean)+relu -> SAGEConv(mean) -> log_softmax
// N=100000, E=1.6M, dims 128 -> 128 -> 128 -> 64.
//
// Round 6: (a) conv2 restructured GEMM-first (mean is linear): gemm_dual emits
// g2=h2@Wl^T (bf16, 64 cols) + r2=h2@Wr^T+b (f32); gather_out gathers 128B rows,
// adds r2, fused log_softmax. (b) gathers rebuilt for MLP: 4 (or 8) edge-groups
// per 64-lane wave, bf16x8 loads, 8-16 requests in flight, shfl_xor group reduce.
// CSR build: two-level multisplit (round 5). GEMMs: bf16 MFMA 16x16x32.

#define KDIM 128
#define CH 16384            // edges per multisplit chunk
#define BSH 8               // bucket = dst >> 8 (256 nodes/bucket)
#define BCAP 8192           // per-bucket LDS capacity (avg ~4100)

using bf16x8 = __attribute__((ext_vector_type(8))) short;
using f32x4  = __attribute__((ext_vector_type(4))) float;

__device__ __forceinline__ unsigned short f2bf_u(float f) {
    unsigned u = __float_as_uint(f);
    u += 0x7fffu + ((u >> 16) & 1u);
    return (unsigned short)(u >> 16);
}
__device__ __forceinline__ unsigned packbf2(float a, float b) {
    return (unsigned)f2bf_u(a) | ((unsigned)f2bf_u(b) << 16);
}
__device__ __forceinline__ float bf2f(short s) {
    return __uint_as_float(((unsigned)(unsigned short)s) << 16);
}

__device__ __forceinline__ void gload_lds16(const short* g, short* l) {
    __builtin_amdgcn_global_load_lds(
        (const __attribute__((address_space(1))) unsigned int*)g,
        (__attribute__((address_space(3))) unsigned int*)l, 16, 0, 0);
}

// ---- multisplit CSR build ----

__global__ __launch_bounds__(256) void bin_hist(
    const int* __restrict__ ei, int* __restrict__ hist, int E, int nwg, int NB)
{
    __shared__ int lh[512];
    const int w = blockIdx.x, t = threadIdx.x;
    for (int b = t; b < NB; b += 256) lh[b] = 0;
    __syncthreads();
    const int e0 = w * CH, e1 = min(E, e0 + CH);
    for (int e = e0 + t; e < e1; e += 256)
        atomicAdd(&lh[ei[E + e] >> BSH], 1);
    __syncthreads();
    for (int b = t; b < NB; b += 256) hist[b * nwg + w] = lh[b];
}

__global__ __launch_bounds__(256) void greduce(
    const int* __restrict__ in, int* __restrict__ bsum, int n)
{
    const int t = threadIdx.x;
    const int idx = blockIdx.x * 1024 + t * 4;
    int s = 0;
    if (idx + 4 <= n) {
        int4 a = *(const int4*)(in + idx);
        s = a.x + a.y + a.z + a.w;
    } else {
        #pragma unroll
        for (int k = 0; k < 4; ++k) if (idx + k < n) s += in[idx + k];
    }
    #pragma unroll
    for (int d = 1; d < 64; d <<= 1) s += __shfl_xor(s, d);
    __shared__ int ws[4];
    if ((t & 63) == 0) ws[t >> 6] = s;
    __syncthreads();
    if (t == 0) bsum[blockIdx.x] = ws[0] + ws[1] + ws[2] + ws[3];
}

__global__ __launch_bounds__(256) void scan_bsums(int* __restrict__ bsum, int nb)
{
    const int t = threadIdx.x;
    const int lane = t & 63, wid = t >> 6;
    int v = (t < nb) ? bsum[t] : 0;
    int incl = v;
    #pragma unroll
    for (int d = 1; d < 64; d <<= 1) {
        int u = __shfl_up(incl, d);
        if (lane >= d) incl += u;
    }
    __shared__ int ws[4];
    if (lane == 63) ws[wid] = incl;
    __syncthreads();
    int woff = 0;
    #pragma unroll
    for (int w = 0; w < 4; ++w) if (w < wid) woff += ws[w];
    const int excl = woff + incl - v;
    if (t <= nb) bsum[t] = excl;
}

__global__ __launch_bounds__(256) void gapply(
    int* __restrict__ io, const int* __restrict__ bsum, int n)
{
    const int t = threadIdx.x;
    const int lane = t & 63, wid = t >> 6;
    const int idx = blockIdx.x * 1024 + t * 4;
    int v[4] = {0, 0, 0, 0};
    if (idx + 4 <= n) {
        int4 a = *(const int4*)(io + idx);
        v[0] = a.x; v[1] = a.y; v[2] = a.z; v[3] = a.w;
    } else {
        #pragma unroll
        for (int k = 0; k < 4; ++k) if (idx + k < n) v[k] = io[idx + k];
    }
    const int sum = v[0] + v[1] + v[2] + v[3];
    int incl = sum;
    #pragma unroll
    for (int d = 1; d < 64; d <<= 1) {
        int u = __shfl_up(incl, d);
        if (lane >= d) incl += u;
    }
    __shared__ int ws[4];
    if (lane == 63) ws[wid] = incl;
    __syncthreads();
    int woff = 0;
    #pragma unroll
    for (int w = 0; w < 4; ++w) if (w < wid) woff += ws[w];
    int excl = bsum[blockIdx.x] + woff + (incl - sum);
    if (idx + 4 <= n) {
        int4 o;
        o.x = excl; o.y = excl + v[0]; o.z = excl + v[0] + v[1];
        o.w = excl + v[0] + v[1] + v[2];
        *(int4*)(io + idx) = o;
    } else {
        #pragma unroll
        for (int k = 0; k < 4; ++k) {
            if (idx + k < n) { io[idx + k] = excl; excl += v[k]; }
        }
    }
}

__global__ __launch_bounds__(256) void bin_scatter(
    const int* __restrict__ ei, const int* __restrict__ hist_s,
    unsigned* __restrict__ packed, int E, int nwg, int NB)
{
    __shared__ int lc[512];
    const int w = blockIdx.x, t = threadIdx.x;
    for (int b = t; b < NB; b += 256) lc[b] = hist_s[b * nwg + w];
    __syncthreads();
    const int e0 = w * CH, e1 = min(E, e0 + CH);
    for (int e = e0 + t; e < e1; e += 256) {
        const int src = ei[e];
        const int dst = ei[E + e];
        const int b = dst >> BSH;
        const int pos = atomicAdd(&lc[b], 1);
        packed[pos] = ((unsigned)(dst & 255) << 17) | (unsigned)src;
    }
}

__global__ __launch_bounds__(256) void bucket_sort(
    const unsigned* __restrict__ packed, const int* __restrict__ hist_s,
    int* __restrict__ offs, float* __restrict__ degf, int* __restrict__ perm,
    int E, int nwg, int NB, int N)
{
    __shared__ unsigned le[BCAP];
    __shared__ int lp[BCAP];
    __shared__ int lh[256], lx[256], lc[256];
    __shared__ int ws[4];
    const int b = blockIdx.x, t = threadIdx.x;
    const int bb = hist_s[b * nwg];
    const int be = (b + 1 < NB) ? hist_s[(b + 1) * nwg] : E;
    int cnt = be - bb;
    if (cnt > BCAP) cnt = BCAP;
    for (int i = t; i < cnt; i += 256) le[i] = packed[bb + i];
    lh[t] = 0;
    __syncthreads();
    for (int i = t; i < cnt; i += 256) atomicAdd(&lh[le[i] >> 17], 1);
    __syncthreads();
    const int lane = t & 63, wid = t >> 6;
    const int v = lh[t];
    int incl = v;
    #pragma unroll
    for (int d = 1; d < 64; d <<= 1) {
        int u = __shfl_up(incl, d);
        if (lane >= d) incl += u;
    }
    if (lane == 63) ws[wid] = incl;
    __syncthreads();
    int woff = 0;
    #pragma unroll
    for (int w = 0; w < 4; ++w) if (w < wid) woff += ws[w];
    const int excl = woff + incl - v;
    lx[t] = excl;
    lc[t] = excl;
    __syncthreads();
    for (int i = t; i < cnt; i += 256) {
        const unsigned p = le[i];
        const int pos = atomicAdd(&lc[p >> 17], 1);
        lp[pos] = (int)(p & 0x1FFFFu);
    }
    __syncthreads();
    for (int i = t; i < cnt; i += 256) perm[bb + i] = lp[i];
    const int node = (b << BSH) + t;
    if (node < N) {
        offs[node] = bb + lx[t];
        degf[node] = (float)v;
    }
    if (b == NB - 1 && t == 0) offs[N] = E;
}

// ---- operand prep ----

__global__ __launch_bounds__(256) void cvt_f32_bf16(
    const float* __restrict__ x, short* __restrict__ y, long n4)
{
    long i = (long)blockIdx.x * 256 + threadIdx.x;
    long stride = (long)gridDim.x * 256;
    const float4* x4 = (const float4*)x;
    for (long j = i; j < n4; j += stride) {
        float4 v = x4[j];
        uint2 o;
        o.x = packbf2(v.x, v.y);
        o.y = packbf2(v.z, v.w);
        *(uint2*)(y + j * 4) = o;
    }
}

// wp[ks][cf][lane][j] = bf16(W[cf*16 + (lane&15)][ks*32 + (lane>>4)*8 + j])
__global__ __launch_bounds__(256) void pack_weights(
    const float* __restrict__ Wlin, const float* __restrict__ Wc1l,
    const float* __restrict__ Wc1r, const float* __restrict__ Wc2l,
    const float* __restrict__ Wc2r, short* __restrict__ wp)
{
    int idx = blockIdx.x * 256 + threadIdx.x;   // 0..65535
    if (idx >= 65536) return;
    const float* W; short* dst; int off, ncf;
    if (idx < 16384)      { W = Wlin; dst = wp;         off = idx;         ncf = 8; }
    else if (idx < 32768) { W = Wc1l; dst = wp + 16384; off = idx - 16384; ncf = 8; }
    else if (idx < 49152) { W = Wc1r; dst = wp + 32768; off = idx - 32768; ncf = 8; }
    else if (idx < 57344) { W = Wc2l; dst = wp + 49152; off = idx - 49152; ncf = 4; }
    else                  { W = Wc2r; dst = wp + 57344; off = idx - 57344; ncf = 4; }
    int j    = off & 7;
    int lane = (off >> 3) & 63;
    int cf   = (off >> 9) & (ncf - 1);
    int ks   = off >> ((ncf == 8) ? 12 : 11);
    int m = cf * 16 + (lane & 15);
    int k = ks * 32 + ((lane >> 4) << 3) + j;
    dst[off] = (short)f2bf_u(W[m * KDIM + k]);
}

// ---- gathers ----

// conv1: one wave per node; 4 edge-groups x 16 lanes x 16B (full 128-col row).
// agg[n] = bf16( sum_j h[j] / max(deg,1) )
__global__ __launch_bounds__(256) void gather_mean_128(
    const short* __restrict__ h, const int* __restrict__ offs,
    const int* __restrict__ perm, const float* __restrict__ degf,
    short* __restrict__ agg, int N)
{
    const int node = blockIdx.x * 4 + (threadIdx.x >> 6);
    if (node >= N) return;
    const int l = threadIdx.x & 63;
    const int g = l >> 4;            // edge group 0..3
    const int c = l & 15;            // 16B chunk within row
    const int b = offs[node], e = offs[node + 1];
    float acc[8] = {0.f, 0.f, 0.f, 0.f, 0.f, 0.f, 0.f, 0.f};
    for (int i = b; i < e; i += 8) {
        const int i0 = i + g, i1 = i + 4 + g;
        bf16x8 v0 = {0, 0, 0, 0, 0, 0, 0, 0};
        bf16x8 v1 = {0, 0, 0, 0, 0, 0, 0, 0};
        if (i0 < e) v0 = *(const bf16x8*)(h + (long)perm[i0] * KDIM + c * 8);
        if (i1 < e) v1 = *(const bf16x8*)(h + (long)perm[i1] * KDIM + c * 8);
        #pragma unroll
        for (int q = 0; q < 8; ++q) acc[q] += bf2f(v0[q]) + bf2f(v1[q]);
    }
    #pragma unroll
    for (int q = 0; q < 8; ++q) {
        acc[q] += __shfl_xor(acc[q], 16);
        acc[q] += __shfl_xor(acc[q], 32);
    }
    if (g == 0) {
        const float inv = 1.f / fmaxf(degf[node], 1.f);
        uint4 o;
        o.x = packbf2(acc[0] * inv, acc[1] * inv);
        o.y = packbf2(acc[2] * inv, acc[3] * inv);
        o.z = packbf2(acc[4] * inv, acc[5] * inv);
        o.w = packbf2(acc[6] * inv, acc[7] * inv);
        *(uint4*)(agg + (long)node * KDIM + c * 8) = o;
    }
}

// conv2 tail: one wave per node; 8 edge-groups x 8 lanes x 16B (full 64-col g2 row).
// out[n] = log_softmax( sum_j g2[j]/max(deg,1) + r2[n] )
__global__ __launch_bounds__(256) void gather_out(
    const short* __restrict__ g2, const float* __restrict__ r2,
    const int* __restrict__ offs, const int* __restrict__ perm,
    const float* __restrict__ degf, float* __restrict__ out, int N)
{
    const int node = blockIdx.x * 4 + (threadIdx.x >> 6);
    if (node >= N) return;
    const int l = threadIdx.x & 63;
    const int g = l >> 3;            // edge group 0..7
    const int c = l & 7;             // 16B chunk within 64-col row
    const int b = offs[node], e = offs[node + 1];
    float acc[8] = {0.f, 0.f, 0.f, 0.f, 0.f, 0.f, 0.f, 0.f};
    for (int i = b; i < e; i += 16) {
        const int i0 = i + g, i1 = i + 8 + g;
        bf16x8 v0 = {0, 0, 0, 0, 0, 0, 0, 0};
        bf16x8 v1 = {0, 0, 0, 0, 0, 0, 0, 0};
        if (i0 < e) v0 = *(const bf16x8*)(g2 + (long)perm[i0] * 64 + c * 8);
        if (i1 < e) v1 = *(const bf16x8*)(g2 + (long)perm[i1] * 64 + c * 8);
        #pragma unroll
        for (int q = 0; q < 8; ++q) acc[q] += bf2f(v0[q]) + bf2f(v1[q]);
    }
    #pragma unroll
    for (int q = 0; q < 8; ++q) {
        acc[q] += __shfl_xor(acc[q], 8);
        acc[q] += __shfl_xor(acc[q], 16);
        acc[q] += __shfl_xor(acc[q], 32);
    }
    const float inv = 1.f / fmaxf(degf[node], 1.f);
    const float4 ra = *(const float4*)(r2 + (long)node * 64 + c * 8);
    const float4 rb = *(const float4*)(r2 + (long)node * 64 + c * 8 + 4);
    float v[8];
    v[0] = acc[0] * inv + ra.x; v[1] = acc[1] * inv + ra.y;
    v[2] = acc[2] * inv + ra.z; v[3] = acc[3] * inv + ra.w;
    v[4] = acc[4] * inv + rb.x; v[5] = acc[5] * inv + rb.y;
    v[6] = acc[6] * inv + rb.z; v[7] = acc[7] * inv + rb.w;
    float m = v[0];
    #pragma unroll
    for (int q = 1; q < 8; ++q) m = fmaxf(m, v[q]);
    m = fmaxf(m, __shfl_xor(m, 1));
    m = fmaxf(m, __shfl_xor(m, 2));
    m = fmaxf(m, __shfl_xor(m, 4));
    float s = 0.f;
    #pragma unroll
    for (int q = 0; q < 8; ++q) s += expf(v[q] - m);
    s += __shfl_xor(s, 1);
    s += __shfl_xor(s, 2);
    s += __shfl_xor(s, 4);
    const float L = m + logf(s);
    if (g == 0) {
        float4 oa = make_float4(v[0] - L, v[1] - L, v[2] - L, v[3] - L);
        float4 ob = make_float4(v[4] - L, v[5] - L, v[6] - L, v[7] - L);
        *(float4*)(out + (long)node * 64 + c * 8) = oa;
        *(float4*)(out + (long)node * 64 + c * 8 + 4) = ob;
    }
}

// ---- GEMMs ----

// out = act( A @ WA^T + bias [+ B @ WB^T] ), 64-row tile, 4 waves. NCF=8 only here.
template<int NCF, bool HAS_B, int ACT>
__global__ __launch_bounds__(256) void gemm_mfma(
    const short* __restrict__ A, const short* __restrict__ B,
    const short* __restrict__ wpA, const short* __restrict__ wpB,
    const float* __restrict__ bias, void* __restrict__ outp, int N)
{
    constexpr int CFW = (NCF == 8) ? 2 : 4;
    constexpr int RFW = (NCF == 8) ? 4 : 1;
    __shared__ __attribute__((aligned(16))) short xa[64 * KDIM];
    __shared__ __attribute__((aligned(16))) short xb[HAS_B ? 64 * KDIM : 8];

    const int t = threadIdx.x;
    const int w = t >> 6, lane = t & 63;
    const int row0 = blockIdx.x * 64;
    const int cf0 = (NCF == 8) ? w * 2 : 0;
    const int rf0 = (NCF == 8) ? 0 : w;

    bf16x8 bwA[4][CFW];
    bf16x8 bwB[HAS_B ? 4 : 1][HAS_B ? CFW : 1];
    #pragma unroll
    for (int ks = 0; ks < 4; ++ks)
        #pragma unroll
        for (int c = 0; c < CFW; ++c) {
            bwA[ks][c] = *(const bf16x8*)(wpA + (((ks * NCF) + cf0 + c) * 64 + lane) * 8);
            if (HAS_B)
                bwB[ks][c] = *(const bf16x8*)(wpB + (((ks * NCF) + cf0 + c) * 64 + lane) * 8);
        }

    #pragma unroll
    for (int ii = 0; ii < 4; ++ii) {
        const int i = w * 4 + ii;
        const int rl = i * 4 + (lane >> 4);
        const int grow = min(row0 + rl, N - 1);
        const int gs = (lane & 15) ^ (rl & 7);
        gload_lds16(A + (long)grow * KDIM + gs * 8, &xa[i * 512]);
        if (HAS_B) gload_lds16(B + (long)grow * KDIM + gs * 8, &xb[i * 512]);
    }

    f32x4 acc[RFW][CFW];
    #pragma unroll
    for (int c = 0; c < CFW; ++c) {
        const float bv = bias[(cf0 + c) * 16 + (lane & 15)];
        #pragma unroll
        for (int rf = 0; rf < RFW; ++rf)
            acc[rf][c] = f32x4{bv, bv, bv, bv};
    }

    __syncthreads();

    #pragma unroll
    for (int ks = 0; ks < 4; ++ks) {
        #pragma unroll
        for (int rf = 0; rf < RFW; ++rf) {
            const int rl = (rf0 + rf) * 16 + (lane & 15);
            const int s = (ks * 4 + (lane >> 4)) ^ (rl & 7);
            const bf16x8 a = *(const bf16x8*)(xa + rl * KDIM + s * 8);
            #pragma unroll
            for (int c = 0; c < CFW; ++c)
                acc[rf][c] = __builtin_amdgcn_mfma_f32_16x16x32_bf16(
                    a, bwA[ks][c], acc[rf][c], 0, 0, 0);
            if (HAS_B) {
                const bf16x8 bb = *(const bf16x8*)(xb + rl * KDIM + s * 8);
                #pragma unroll
                for (int c = 0; c < CFW; ++c)
                    acc[rf][c] = __builtin_amdgcn_mfma_f32_16x16x32_bf16(
                        bb, bwB[ks][c], acc[rf][c], 0, 0, 0);
            }
        }
    }

    short* out = (short*)outp;
    #pragma unroll
    for (int rf = 0; rf < RFW; ++rf)
        #pragma unroll
        for (int c = 0; c < CFW; ++c)
            #pragma unroll
            for (int q = 0; q < 4; ++q) {
                const int row = row0 + (rf0 + rf) * 16 + (lane >> 4) * 4 + q;
                if (row < N) {
                    float v = acc[rf][c][q];
                    if (ACT == 1) v = fmaxf(v, 0.f);
                    out[(long)row * (NCF * 16) + (cf0 + c) * 16 + (lane & 15)] =
                        (short)f2bf_u(v);
                }
            }
}

// conv2 dual GEMM: g2 = A @ Wl^T (bf16, no bias), r2 = A @ Wr^T + b (f32).
// 64-row tile, 4 waves: waves 0,1 -> Wl side; waves 2,3 -> Wr side; 2 col-frags each.
__global__ __launch_bounds__(256) void gemm_dual(
    const short* __restrict__ A, const short* __restrict__ wpL,
    const short* __restrict__ wpR, const float* __restrict__ bias,
    short* __restrict__ g2, float* __restrict__ r2, int N)
{
    __shared__ __attribute__((aligned(16))) short xa[64 * KDIM];
    const int t = threadIdx.x;
    const int w = t >> 6, lane = t & 63;
    const int row0 = blockIdx.x * 64;
    const int side = w >> 1;
    const int cf0 = (w & 1) * 2;
    const short* wpS = side ? wpR : wpL;

    bf16x8 bw[4][2];
    #pragma unroll
    for (int ks = 0; ks < 4; ++ks)
        #pragma unroll
        for (int c = 0; c < 2; ++c)
            bw[ks][c] = *(const bf16x8*)(wpS + (((ks * 4) + cf0 + c) * 64 + lane) * 8);

    #pragma unroll
    for (int ii = 0; ii < 4; ++ii) {
        const int i = w * 4 + ii;
        const int rl = i * 4 + (lane >> 4);
        const int grow = min(row0 + rl, N - 1);
        const int gs = (lane & 15) ^ (rl & 7);
        gload_lds16(A + (long)grow * KDIM + gs * 8, &xa[i * 512]);
    }

    f32x4 acc[4][2];
    #pragma unroll
    for (int c = 0; c < 2; ++c) {
        const float bv = side ? bias[(cf0 + c) * 16 + (lane & 15)] : 0.f;
        #pragma unroll
        for (int rf = 0; rf < 4; ++rf)
            acc[rf][c] = f32x4{bv, bv, bv, bv};
    }

    __syncthreads();

    #pragma unroll
    for (int ks = 0; ks < 4; ++ks) {
        #pragma unroll
        for (int rf = 0; rf < 4; ++rf) {
            const int rl = rf * 16 + (lane & 15);
            const int s = (ks * 4 + (lane >> 4)) ^ (rl & 7);
            const bf16x8 a = *(const bf16x8*)(xa + rl * KDIM + s * 8);
            #pragma unroll
            for (int c = 0; c < 2; ++c)
                acc[rf][c] = __builtin_amdgcn_mfma_f32_16x16x32_bf16(
                    a, bw[ks][c], acc[rf][c], 0, 0, 0);
        }
    }

    #pragma unroll
    for (int rf = 0; rf < 4; ++rf)
        #pragma unroll
        for (int c = 0; c < 2; ++c)
            #pragma unroll
            for (int q = 0; q < 4; ++q) {
                const int row = row0 + rf * 16 + (lane >> 4) * 4 + q;
                if (row < N) {
                    const int col = (cf0 + c) * 16 + (lane & 15);
                    if (side == 0)
                        g2[(long)row * 64 + col] = (short)f2bf_u(acc[rf][c][q]);
                    else
                        r2[(long)row * 64 + col] = acc[rf][c][q];
                }
            }
}

extern "C" void kernel_launch(void* const* d_in, const int* in_sizes, int n_in,
                              void* d_out, int out_size, void* d_ws, size_t ws_size,
                              hipStream_t stream) {
    const float* x     = (const float*)d_in[0];
    const int*   ei    = (const int*)d_in[1];
    const float* lin_W = (const float*)d_in[2];
    const float* lin_b = (const float*)d_in[3];
    const float* c1_Wl = (const float*)d_in[4];
    const float* c1_bl = (const float*)d_in[5];
    const float* c1_Wr = (const float*)d_in[6];
    const float* c2_Wl = (const float*)d_in[7];
    const float* c2_bl = (const float*)d_in[8];
    const float* c2_Wr = (const float*)d_in[9];
    float* out = (float*)d_out;

    const int N = in_sizes[0] / KDIM;
    const int E = in_sizes[1] / 2;

    short* xb16 = (short*)d_ws;                  // N*128 bf16
    short* h1   = xb16 + (size_t)N * KDIM;       // N*128 bf16
    short* h2   = h1 + (size_t)N * KDIM;         // N*128 bf16
    short* aggb = h2 + (size_t)N * KDIM;         // N*128 bf16
    short* g2   = aggb + (size_t)N * KDIM;       // N*64 bf16
    float* r2   = (float*)(g2 + (size_t)N * 64); // N*64 f32
    short* wp   = (short*)(r2 + (size_t)N * 64); // 65536 bf16
    float* degf = (float*)(wp + 65536);          // N f32
    int* offs   = (int*)(degf + N);              // N+1
    const int nwg = (E + CH - 1) / CH;           // 98
    const int NB  = (N + 255) >> BSH;            // 391
    int* hist   = offs + (N + 1);                // NB*nwg
    int* bsum   = hist + NB * nwg;               // 256
    unsigned* packed = (unsigned*)(bsum + 256);  // E
    int* perm   = (int*)(packed + E);            // E

    const int nb = (N + 63) / 64;
    const int gb = (N + 3) / 4;
    const int nh = NB * nwg;
    const int nsb = (nh + 1023) / 1024;

    // ---- CSR build: two-level multisplit (no global atomics) ----
    bin_hist<<<nwg, 256, 0, stream>>>(ei, hist, E, nwg, NB);
    greduce<<<nsb, 256, 0, stream>>>(hist, bsum, nh);
    scan_bsums<<<1, 256, 0, stream>>>(bsum, nsb);
    gapply<<<nsb, 256, 0, stream>>>(hist, bsum, nh);
    bin_scatter<<<nwg, 256, 0, stream>>>(ei, hist, packed, E, nwg, NB);
    bucket_sort<<<NB, 256, 0, stream>>>(packed, hist, offs, degf, perm, E, nwg, NB, N);

    // ---- operand prep ----
    cvt_f32_bf16<<<1024, 256, 0, stream>>>(x, xb16, (long)N * KDIM / 4);
    pack_weights<<<256, 256, 0, stream>>>(lin_W, c1_Wl, c1_Wr, c2_Wl, c2_Wr, wp);

    // layer 1: h1 = relu(x @ lin_W^T + lin_b)
    gemm_mfma<8, false, 1><<<nb, 256, 0, stream>>>(
        xb16, nullptr, wp, nullptr, lin_b, h1, N);

    // conv1: agg = mean_{j->i} h1[j];  h2 = relu(agg @ Wl^T + b + h1 @ Wr^T)
    gather_mean_128<<<gb, 256, 0, stream>>>(h1, offs, perm, degf, aggb, N);
    gemm_mfma<8, true, 1><<<nb, 256, 0, stream>>>(
        aggb, h1, wp + 16384, wp + 32768, c1_bl, h2, N);

    // conv2: g2 = h2 @ Wl^T (bf16), r2 = h2 @ Wr^T + b (f32);
    // out = log_softmax(gather_mean(g2) + r2)
    gemm_dual<<<nb, 256, 0, stream>>>(h2, wp + 49152, wp + 57344, c2_bl, g2, r2, N);
    gather_out<<<gb, 256, 0, stream>>>(g2, r2, offs, perm, degf, out, N);
}

// Round 7
// 220.256 us; speedup vs baseline: 26.2330x; 1.0882x over previous
//
#include <hip/hip_runtime.h>

// GraphSAGE forward: lin+relu -> SAGEConv(mean)+relu -> SAGEConv(mean) -> log_softmax
// N=100000, E=1.6M, dims 128 -> 128 -> 128 -> 64.
//
// Round 7: (a) cvt kernel deleted -- gemm_lin stages f32 x directly (reg cvt +
// swizzled ds_write); (b) gathers: branch-free 16-edge main loop (4 loads in
// flight, no cndmask), predicated tail only; (c) r2 stored bf16.
// CSR build: two-level multisplit. GEMMs: bf16 MFMA 16x16x32, fragment-packed W.

#define KDIM 128
#define CH 16384            // edges per multisplit chunk
#define BSH 8               // bucket = dst >> 8 (256 nodes/bucket)
#define BCAP 8192           // per-bucket LDS capacity (avg ~4100)

using bf16x8 = __attribute__((ext_vector_type(8))) short;
using f32x4  = __attribute__((ext_vector_type(4))) float;

__device__ __forceinline__ unsigned short f2bf_u(float f) {
    unsigned u = __float_as_uint(f);
    u += 0x7fffu + ((u >> 16) & 1u);
    return (unsigned short)(u >> 16);
}
__device__ __forceinline__ unsigned packbf2(float a, float b) {
    return (unsigned)f2bf_u(a) | ((unsigned)f2bf_u(b) << 16);
}
__device__ __forceinline__ float bf2f(short s) {
    return __uint_as_float(((unsigned)(unsigned short)s) << 16);
}

__device__ __forceinline__ void gload_lds16(const short* g, short* l) {
    __builtin_amdgcn_global_load_lds(
        (const __attribute__((address_space(1))) unsigned int*)g,
        (__attribute__((address_space(3))) unsigned int*)l, 16, 0, 0);
}

// ---- multisplit CSR build ----

__global__ __launch_bounds__(256) void bin_hist(
    const int* __restrict__ ei, int* __restrict__ hist, int E, int nwg, int NB)
{
    __shared__ int lh[512];
    const int w = blockIdx.x, t = threadIdx.x;
    for (int b = t; b < NB; b += 256) lh[b] = 0;
    __syncthreads();
    const int e0 = w * CH, e1 = min(E, e0 + CH);
    for (int e = e0 + t; e < e1; e += 256)
        atomicAdd(&lh[ei[E + e] >> BSH], 1);
    __syncthreads();
    for (int b = t; b < NB; b += 256) hist[b * nwg + w] = lh[b];
}

__global__ __launch_bounds__(256) void greduce(
    const int* __restrict__ in, int* __restrict__ bsum, int n)
{
    const int t = threadIdx.x;
    const int idx = blockIdx.x * 1024 + t * 4;
    int s = 0;
    if (idx + 4 <= n) {
        int4 a = *(const int4*)(in + idx);
        s = a.x + a.y + a.z + a.w;
    } else {
        #pragma unroll
        for (int k = 0; k < 4; ++k) if (idx + k < n) s += in[idx + k];
    }
    #pragma unroll
    for (int d = 1; d < 64; d <<= 1) s += __shfl_xor(s, d);
    __shared__ int ws[4];
    if ((t & 63) == 0) ws[t >> 6] = s;
    __syncthreads();
    if (t == 0) bsum[blockIdx.x] = ws[0] + ws[1] + ws[2] + ws[3];
}

__global__ __launch_bounds__(256) void scan_bsums(int* __restrict__ bsum, int nb)
{
    const int t = threadIdx.x;
    const int lane = t & 63, wid = t >> 6;
    int v = (t < nb) ? bsum[t] : 0;
    int incl = v;
    #pragma unroll
    for (int d = 1; d < 64; d <<= 1) {
        int u = __shfl_up(incl, d);
        if (lane >= d) incl += u;
    }
    __shared__ int ws[4];
    if (lane == 63) ws[wid] = incl;
    __syncthreads();
    int woff = 0;
    #pragma unroll
    for (int w = 0; w < 4; ++w) if (w < wid) woff += ws[w];
    const int excl = woff + incl - v;
    if (t <= nb) bsum[t] = excl;
}

__global__ __launch_bounds__(256) void gapply(
    int* __restrict__ io, const int* __restrict__ bsum, int n)
{
    const int t = threadIdx.x;
    const int lane = t & 63, wid = t >> 6;
    const int idx = blockIdx.x * 1024 + t * 4;
    int v[4] = {0, 0, 0, 0};
    if (idx + 4 <= n) {
        int4 a = *(const int4*)(io + idx);
        v[0] = a.x; v[1] = a.y; v[2] = a.z; v[3] = a.w;
    } else {
        #pragma unroll
        for (int k = 0; k < 4; ++k) if (idx + k < n) v[k] = io[idx + k];
    }
    const int sum = v[0] + v[1] + v[2] + v[3];
    int incl = sum;
    #pragma unroll
    for (int d = 1; d < 64; d <<= 1) {
        int u = __shfl_up(incl, d);
        if (lane >= d) incl += u;
    }
    __shared__ int ws[4];
    if (lane == 63) ws[wid] = incl;
    __syncthreads();
    int woff = 0;
    #pragma unroll
    for (int w = 0; w < 4; ++w) if (w < wid) woff += ws[w];
    int excl = bsum[blockIdx.x] + woff + (incl - sum);
    if (idx + 4 <= n) {
        int4 o;
        o.x = excl; o.y = excl + v[0]; o.z = excl + v[0] + v[1];
        o.w = excl + v[0] + v[1] + v[2];
        *(int4*)(io + idx) = o;
    } else {
        #pragma unroll
        for (int k = 0; k < 4; ++k) {
            if (idx + k < n) { io[idx + k] = excl; excl += v[k]; }
        }
    }
}

__global__ __launch_bounds__(256) void bin_scatter(
    const int* __restrict__ ei, const int* __restrict__ hist_s,
    unsigned* __restrict__ packed, int E, int nwg, int NB)
{
    __shared__ int lc[512];
    const int w = blockIdx.x, t = threadIdx.x;
    for (int b = t; b < NB; b += 256) lc[b] = hist_s[b * nwg + w];
    __syncthreads();
    const int e0 = w * CH, e1 = min(E, e0 + CH);
    for (int e = e0 + t; e < e1; e += 256) {
        const int src = ei[e];
        const int dst = ei[E + e];
        const int b = dst >> BSH;
        const int pos = atomicAdd(&lc[b], 1);
        packed[pos] = ((unsigned)(dst & 255) << 17) | (unsigned)src;
    }
}

__global__ __launch_bounds__(256) void bucket_sort(
    const unsigned* __restrict__ packed, const int* __restrict__ hist_s,
    int* __restrict__ offs, float* __restrict__ degf, int* __restrict__ perm,
    int E, int nwg, int NB, int N)
{
    __shared__ unsigned le[BCAP];
    __shared__ int lp[BCAP];
    __shared__ int lh[256], lx[256], lc[256];
    __shared__ int ws[4];
    const int b = blockIdx.x, t = threadIdx.x;
    const int bb = hist_s[b * nwg];
    const int be = (b + 1 < NB) ? hist_s[(b + 1) * nwg] : E;
    int cnt = be - bb;
    if (cnt > BCAP) cnt = BCAP;
    for (int i = t; i < cnt; i += 256) le[i] = packed[bb + i];
    lh[t] = 0;
    __syncthreads();
    for (int i = t; i < cnt; i += 256) atomicAdd(&lh[le[i] >> 17], 1);
    __syncthreads();
    const int lane = t & 63, wid = t >> 6;
    const int v = lh[t];
    int incl = v;
    #pragma unroll
    for (int d = 1; d < 64; d <<= 1) {
        int u = __shfl_up(incl, d);
        if (lane >= d) incl += u;
    }
    if (lane == 63) ws[wid] = incl;
    __syncthreads();
    int woff = 0;
    #pragma unroll
    for (int w = 0; w < 4; ++w) if (w < wid) woff += ws[w];
    const int excl = woff + incl - v;
    lx[t] = excl;
    lc[t] = excl;
    __syncthreads();
    for (int i = t; i < cnt; i += 256) {
        const unsigned p = le[i];
        const int pos = atomicAdd(&lc[p >> 17], 1);
        lp[pos] = (int)(p & 0x1FFFFu);
    }
    __syncthreads();
    for (int i = t; i < cnt; i += 256) perm[bb + i] = lp[i];
    const int node = (b << BSH) + t;
    if (node < N) {
        offs[node] = bb + lx[t];
        degf[node] = (float)v;
    }
    if (b == NB - 1 && t == 0) offs[N] = E;
}

// ---- operand prep ----

// wp[ks][cf][lane][j] = bf16(W[cf*16 + (lane&15)][ks*32 + (lane>>4)*8 + j])
__global__ __launch_bounds__(256) void pack_weights(
    const float* __restrict__ Wlin, const float* __restrict__ Wc1l,
    const float* __restrict__ Wc1r, const float* __restrict__ Wc2l,
    const float* __restrict__ Wc2r, short* __restrict__ wp)
{
    int idx = blockIdx.x * 256 + threadIdx.x;   // 0..65535
    if (idx >= 65536) return;
    const float* W; short* dst; int off, ncf;
    if (idx < 16384)      { W = Wlin; dst = wp;         off = idx;         ncf = 8; }
    else if (idx < 32768) { W = Wc1l; dst = wp + 16384; off = idx - 16384; ncf = 8; }
    else if (idx < 49152) { W = Wc1r; dst = wp + 32768; off = idx - 32768; ncf = 8; }
    else if (idx < 57344) { W = Wc2l; dst = wp + 49152; off = idx - 49152; ncf = 4; }
    else                  { W = Wc2r; dst = wp + 57344; off = idx - 57344; ncf = 4; }
    int j    = off & 7;
    int lane = (off >> 3) & 63;
    int cf   = (off >> 9) & (ncf - 1);
    int ks   = off >> ((ncf == 8) ? 12 : 11);
    int m = cf * 16 + (lane & 15);
    int k = ks * 32 + ((lane >> 4) << 3) + j;
    dst[off] = (short)f2bf_u(W[m * KDIM + k]);
}

// ---- gathers ----

// conv1: one wave per node; 4 edge-groups x 16 lanes x 16B (full 128-col row).
// Branch-free 16-edge main loop; predicated tail. agg[n] = bf16(sum/max(deg,1)).
__global__ __launch_bounds__(256) void gather_mean_128(
    const short* __restrict__ h, const int* __restrict__ offs,
    const int* __restrict__ perm, const float* __restrict__ degf,
    short* __restrict__ agg, int N)
{
    const int node = blockIdx.x * 4 + (threadIdx.x >> 6);
    if (node >= N) return;
    const int l = threadIdx.x & 63;
    const int g = l >> 4;            // edge group 0..3
    const int c = l & 15;            // 16B chunk within row
    const int b = offs[node], e = offs[node + 1];
    float acc[8] = {0.f, 0.f, 0.f, 0.f, 0.f, 0.f, 0.f, 0.f};
    int i = b;
    const int e16 = b + (((e - b) >> 4) << 4);
    for (; i < e16; i += 16) {
        const int s0 = perm[i + g],     s1 = perm[i + 4 + g];
        const int s2 = perm[i + 8 + g], s3 = perm[i + 12 + g];
        const bf16x8 v0 = *(const bf16x8*)(h + (long)s0 * KDIM + c * 8);
        const bf16x8 v1 = *(const bf16x8*)(h + (long)s1 * KDIM + c * 8);
        const bf16x8 v2 = *(const bf16x8*)(h + (long)s2 * KDIM + c * 8);
        const bf16x8 v3 = *(const bf16x8*)(h + (long)s3 * KDIM + c * 8);
        #pragma unroll
        for (int q = 0; q < 8; ++q)
            acc[q] += (bf2f(v0[q]) + bf2f(v1[q])) + (bf2f(v2[q]) + bf2f(v3[q]));
    }
    if (i + 8 <= e) {
        const int s0 = perm[i + g], s1 = perm[i + 4 + g];
        const bf16x8 v0 = *(const bf16x8*)(h + (long)s0 * KDIM + c * 8);
        const bf16x8 v1 = *(const bf16x8*)(h + (long)s1 * KDIM + c * 8);
        #pragma unroll
        for (int q = 0; q < 8; ++q) acc[q] += bf2f(v0[q]) + bf2f(v1[q]);
        i += 8;
    }
    {   // tail < 8
        const int i0 = i + g, i1 = i + 4 + g;
        bf16x8 v0 = {0, 0, 0, 0, 0, 0, 0, 0};
        bf16x8 v1 = {0, 0, 0, 0, 0, 0, 0, 0};
        if (i0 < e) v0 = *(const bf16x8*)(h + (long)perm[i0] * KDIM + c * 8);
        if (i1 < e) v1 = *(const bf16x8*)(h + (long)perm[i1] * KDIM + c * 8);
        #pragma unroll
        for (int q = 0; q < 8; ++q) acc[q] += bf2f(v0[q]) + bf2f(v1[q]);
    }
    #pragma unroll
    for (int q = 0; q < 8; ++q) {
        acc[q] += __shfl_xor(acc[q], 16);
        acc[q] += __shfl_xor(acc[q], 32);
    }
    if (g == 0) {
        const float inv = 1.f / fmaxf(degf[node], 1.f);
        uint4 o;
        o.x = packbf2(acc[0] * inv, acc[1] * inv);
        o.y = packbf2(acc[2] * inv, acc[3] * inv);
        o.z = packbf2(acc[4] * inv, acc[5] * inv);
        o.w = packbf2(acc[6] * inv, acc[7] * inv);
        *(uint4*)(agg + (long)node * KDIM + c * 8) = o;
    }
}

// conv2 tail: one wave per node; 8 edge-groups x 8 lanes x 16B (64-col g2 row).
// out[n] = log_softmax( sum_j g2[j]/max(deg,1) + r2[n] ), r2 bf16.
__global__ __launch_bounds__(256) void gather_out(
    const short* __restrict__ g2, const short* __restrict__ r2,
    const int* __restrict__ offs, const int* __restrict__ perm,
    const float* __restrict__ degf, float* __restrict__ out, int N)
{
    const int node = blockIdx.x * 4 + (threadIdx.x >> 6);
    if (node >= N) return;
    const int l = threadIdx.x & 63;
    const int g = l >> 3;            // edge group 0..7
    const int c = l & 7;             // 16B chunk within 64-col row
    const int b = offs[node], e = offs[node + 1];
    float acc[8] = {0.f, 0.f, 0.f, 0.f, 0.f, 0.f, 0.f, 0.f};
    int i = b;
    const int e16 = b + (((e - b) >> 4) << 4);
    for (; i < e16; i += 16) {
        const int s0 = perm[i + g], s1 = perm[i + 8 + g];
        const bf16x8 v0 = *(const bf16x8*)(g2 + (long)s0 * 64 + c * 8);
        const bf16x8 v1 = *(const bf16x8*)(g2 + (long)s1 * 64 + c * 8);
        #pragma unroll
        for (int q = 0; q < 8; ++q) acc[q] += bf2f(v0[q]) + bf2f(v1[q]);
    }
    {   // tail < 16
        const int i0 = i + g, i1 = i + 8 + g;
        bf16x8 v0 = {0, 0, 0, 0, 0, 0, 0, 0};
        bf16x8 v1 = {0, 0, 0, 0, 0, 0, 0, 0};
        if (i0 < e) v0 = *(const bf16x8*)(g2 + (long)perm[i0] * 64 + c * 8);
        if (i1 < e) v1 = *(const bf16x8*)(g2 + (long)perm[i1] * 64 + c * 8);
        #pragma unroll
        for (int q = 0; q < 8; ++q) acc[q] += bf2f(v0[q]) + bf2f(v1[q]);
    }
    #pragma unroll
    for (int q = 0; q < 8; ++q) {
        acc[q] += __shfl_xor(acc[q], 8);
        acc[q] += __shfl_xor(acc[q], 16);
        acc[q] += __shfl_xor(acc[q], 32);
    }
    const float inv = 1.f / fmaxf(degf[node], 1.f);
    const bf16x8 rv = *(const bf16x8*)(r2 + (long)node * 64 + c * 8);
    float v[8];
    #pragma unroll
    for (int q = 0; q < 8; ++q) v[q] = acc[q] * inv + bf2f(rv[q]);
    float m = v[0];
    #pragma unroll
    for (int q = 1; q < 8; ++q) m = fmaxf(m, v[q]);
    m = fmaxf(m, __shfl_xor(m, 1));
    m = fmaxf(m, __shfl_xor(m, 2));
    m = fmaxf(m, __shfl_xor(m, 4));
    float s = 0.f;
    #pragma unroll
    for (int q = 0; q < 8; ++q) s += expf(v[q] - m);
    s += __shfl_xor(s, 1);
    s += __shfl_xor(s, 2);
    s += __shfl_xor(s, 4);
    const float L = m + logf(s);
    if (g == 0) {
        float4 oa = make_float4(v[0] - L, v[1] - L, v[2] - L, v[3] - L);
        float4 ob = make_float4(v[4] - L, v[5] - L, v[6] - L, v[7] - L);
        *(float4*)(out + (long)node * 64 + c * 8) = oa;
        *(float4*)(out + (long)node * 64 + c * 8 + 4) = ob;
    }
}

// ---- GEMMs ----

// layer 1: h1 = relu(x(f32) @ Wlin^T + b) -> bf16. Stages f32 directly:
// reg load (coalesced, swizzle-permuted 32B granules) -> cvt -> ds_write_b128.
__global__ __launch_bounds__(256) void gemm_lin(
    const float* __restrict__ X, const short* __restrict__ wpA,
    const float* __restrict__ bias, short* __restrict__ out, int N)
{
    __shared__ __attribute__((aligned(16))) short xa[64 * KDIM];
    const int t = threadIdx.x;
    const int w = t >> 6, lane = t & 63;
    const int row0 = blockIdx.x * 64;
    const int cf0 = w * 2;

    bf16x8 bwA[4][2];
    #pragma unroll
    for (int ks = 0; ks < 4; ++ks)
        #pragma unroll
        for (int c = 0; c < 2; ++c)
            bwA[ks][c] = *(const bf16x8*)(wpA + (((ks * 8) + cf0 + c) * 64 + lane) * 8);

    // stage: 4 granule-slots per thread; LDS slot (r,s) holds global granule s^(r&7)
    #pragma unroll
    for (int j = 0; j < 4; ++j) {
        const int sl = t + 256 * j;          // 0..1023
        const int r = sl >> 4, s = sl & 15;
        const int gg = s ^ (r & 7);
        const int grow = min(row0 + r, N - 1);
        const float4 f0 = *(const float4*)(X + (long)grow * KDIM + gg * 8);
        const float4 f1 = *(const float4*)(X + (long)grow * KDIM + gg * 8 + 4);
        uint4 o;
        o.x = packbf2(f0.x, f0.y); o.y = packbf2(f0.z, f0.w);
        o.z = packbf2(f1.x, f1.y); o.w = packbf2(f1.z, f1.w);
        *(uint4*)(xa + r * KDIM + s * 8) = o;
    }

    f32x4 acc[4][2];
    #pragma unroll
    for (int c = 0; c < 2; ++c) {
        const float bv = bias[(cf0 + c) * 16 + (lane & 15)];
        #pragma unroll
        for (int rf = 0; rf < 4; ++rf)
            acc[rf][c] = f32x4{bv, bv, bv, bv};
    }

    __syncthreads();

    #pragma unroll
    for (int ks = 0; ks < 4; ++ks) {
        #pragma unroll
        for (int rf = 0; rf < 4; ++rf) {
            const int rl = rf * 16 + (lane & 15);
            const int s = (ks * 4 + (lane >> 4)) ^ (rl & 7);
            const bf16x8 a = *(const bf16x8*)(xa + rl * KDIM + s * 8);
            #pragma unroll
            for (int c = 0; c < 2; ++c)
                acc[rf][c] = __builtin_amdgcn_mfma_f32_16x16x32_bf16(
                    a, bwA[ks][c], acc[rf][c], 0, 0, 0);
        }
    }

    #pragma unroll
    for (int rf = 0; rf < 4; ++rf)
        #pragma unroll
        for (int c = 0; c < 2; ++c)
            #pragma unroll
            for (int q = 0; q < 4; ++q) {
                const int row = row0 + rf * 16 + (lane >> 4) * 4 + q;
                if (row < N)
                    out[(long)row * KDIM + (cf0 + c) * 16 + (lane & 15)] =
                        (short)f2bf_u(fmaxf(acc[rf][c][q], 0.f));
            }
}

// conv1: out = relu( A @ WA^T + bias + B @ WB^T ), A,B bf16 [N][128].
__global__ __launch_bounds__(256) void gemm_c1(
    const short* __restrict__ A, const short* __restrict__ B,
    const short* __restrict__ wpA, const short* __restrict__ wpB,
    const float* __restrict__ bias, short* __restrict__ out, int N)
{
    __shared__ __attribute__((aligned(16))) short xa[64 * KDIM];
    __shared__ __attribute__((aligned(16))) short xb[64 * KDIM];

    const int t = threadIdx.x;
    const int w = t >> 6, lane = t & 63;
    const int row0 = blockIdx.x * 64;
    const int cf0 = w * 2;

    bf16x8 bwA[4][2], bwB[4][2];
    #pragma unroll
    for (int ks = 0; ks < 4; ++ks)
        #pragma unroll
        for (int c = 0; c < 2; ++c) {
            bwA[ks][c] = *(const bf16x8*)(wpA + (((ks * 8) + cf0 + c) * 64 + lane) * 8);
            bwB[ks][c] = *(const bf16x8*)(wpB + (((ks * 8) + cf0 + c) * 64 + lane) * 8);
        }

    #pragma unroll
    for (int ii = 0; ii < 4; ++ii) {
        const int i = w * 4 + ii;
        const int rl = i * 4 + (lane >> 4);
        const int grow = min(row0 + rl, N - 1);
        const int gs = (lane & 15) ^ (rl & 7);
        gload_lds16(A + (long)grow * KDIM + gs * 8, &xa[i * 512]);
        gload_lds16(B + (long)grow * KDIM + gs * 8, &xb[i * 512]);
    }

    f32x4 acc[4][2];
    #pragma unroll
    for (int c = 0; c < 2; ++c) {
        const float bv = bias[(cf0 + c) * 16 + (lane & 15)];
        #pragma unroll
        for (int rf = 0; rf < 4; ++rf)
            acc[rf][c] = f32x4{bv, bv, bv, bv};
    }

    __syncthreads();

    #pragma unroll
    for (int ks = 0; ks < 4; ++ks) {
        #pragma unroll
        for (int rf = 0; rf < 4; ++rf) {
            const int rl = rf * 16 + (lane & 15);
            const int s = (ks * 4 + (lane >> 4)) ^ (rl & 7);
            const bf16x8 a = *(const bf16x8*)(xa + rl * KDIM + s * 8);
            #pragma unroll
            for (int c = 0; c < 2; ++c)
                acc[rf][c] = __builtin_amdgcn_mfma_f32_16x16x32_bf16(
                    a, bwA[ks][c], acc[rf][c], 0, 0, 0);
            const bf16x8 bb = *(const bf16x8*)(xb + rl * KDIM + s * 8);
            #pragma unroll
            for (int c = 0; c < 2; ++c)
                acc[rf][c] = __builtin_amdgcn_mfma_f32_16x16x32_bf16(
                    bb, bwB[ks][c], acc[rf][c], 0, 0, 0);
        }
    }

    #pragma unroll
    for (int rf = 0; rf < 4; ++rf)
        #pragma unroll
        for (int c = 0; c < 2; ++c)
            #pragma unroll
            for (int q = 0; q < 4; ++q) {
                const int row = row0 + rf * 16 + (lane >> 4) * 4 + q;
                if (row < N)
                    out[(long)row * KDIM + (cf0 + c) * 16 + (lane & 15)] =
                        (short)f2bf_u(fmaxf(acc[rf][c][q], 0.f));
            }
}

// conv2 dual GEMM: g2 = A @ Wl^T (bf16), r2 = A @ Wr^T + b (bf16).
// waves 0,1 -> Wl; waves 2,3 -> Wr; 2 col-frags each.
__global__ __launch_bounds__(256) void gemm_dual(
    const short* __restrict__ A, const short* __restrict__ wpL,
    const short* __restrict__ wpR, const float* __restrict__ bias,
    short* __restrict__ g2, short* __restrict__ r2, int N)
{
    __shared__ __attribute__((aligned(16))) short xa[64 * KDIM];
    const int t = threadIdx.x;
    const int w = t >> 6, lane = t & 63;
    const int row0 = blockIdx.x * 64;
    const int side = w >> 1;
    const int cf0 = (w & 1) * 2;
    const short* wpS = side ? wpR : wpL;

    bf16x8 bw[4][2];
    #pragma unroll
    for (int ks = 0; ks < 4; ++ks)
        #pragma unroll
        for (int c = 0; c < 2; ++c)
            bw[ks][c] = *(const bf16x8*)(wpS + (((ks * 4) + cf0 + c) * 64 + lane) * 8);

    #pragma unroll
    for (int ii = 0; ii < 4; ++ii) {
        const int i = w * 4 + ii;
        const int rl = i * 4 + (lane >> 4);
        const int grow = min(row0 + rl, N - 1);
        const int gs = (lane & 15) ^ (rl & 7);
        gload_lds16(A + (long)grow * KDIM + gs * 8, &xa[i * 512]);
    }

    f32x4 acc[4][2];
    #pragma unroll
    for (int c = 0; c < 2; ++c) {
        const float bv = side ? bias[(cf0 + c) * 16 + (lane & 15)] : 0.f;
        #pragma unroll
        for (int rf = 0; rf < 4; ++rf)
            acc[rf][c] = f32x4{bv, bv, bv, bv};
    }

    __syncthreads();

    #pragma unroll
    for (int ks = 0; ks < 4; ++ks) {
        #pragma unroll
        for (int rf = 0; rf < 4; ++rf) {
            const int rl = rf * 16 + (lane & 15);
            const int s = (ks * 4 + (lane >> 4)) ^ (rl & 7);
            const bf16x8 a = *(const bf16x8*)(xa + rl * KDIM + s * 8);
            #pragma unroll
            for (int c = 0; c < 2; ++c)
                acc[rf][c] = __builtin_amdgcn_mfma_f32_16x16x32_bf16(
                    a, bw[ks][c], acc[rf][c], 0, 0, 0);
        }
    }

    short* dst = side ? r2 : g2;
    #pragma unroll
    for (int rf = 0; rf < 4; ++rf)
        #pragma unroll
        for (int c = 0; c < 2; ++c)
            #pragma unroll
            for (int q = 0; q < 4; ++q) {
                const int row = row0 + rf * 16 + (lane >> 4) * 4 + q;
                if (row < N)
                    dst[(long)row * 64 + (cf0 + c) * 16 + (lane & 15)] =
                        (short)f2bf_u(acc[rf][c][q]);
            }
}

extern "C" void kernel_launch(void* const* d_in, const int* in_sizes, int n_in,
                              void* d_out, int out_size, void* d_ws, size_t ws_size,
                              hipStream_t stream) {
    const float* x     = (const float*)d_in[0];
    const int*   ei    = (const int*)d_in[1];
    const float* lin_W = (const float*)d_in[2];
    const float* lin_b = (const float*)d_in[3];
    const float* c1_Wl = (const float*)d_in[4];
    const float* c1_bl = (const float*)d_in[5];
    const float* c1_Wr = (const float*)d_in[6];
    const float* c2_Wl = (const float*)d_in[7];
    const float* c2_bl = (const float*)d_in[8];
    const float* c2_Wr = (const float*)d_in[9];
    float* out = (float*)d_out;

    const int N = in_sizes[0] / KDIM;
    const int E = in_sizes[1] / 2;

    short* h1   = (short*)d_ws;                  // N*128 bf16
    short* h2   = h1 + (size_t)N * KDIM;         // N*128 bf16
    short* aggb = h2 + (size_t)N * KDIM;         // N*128 bf16
    short* g2   = aggb + (size_t)N * KDIM;       // N*64 bf16
    short* r2   = g2 + (size_t)N * 64;           // N*64 bf16
    short* wp   = r2 + (size_t)N * 64;           // 65536 bf16
    float* degf = (float*)(wp + 65536);          // N f32
    int* offs   = (int*)(degf + N);              // N+1
    const int nwg = (E + CH - 1) / CH;           // 98
    const int NB  = (N + 255) >> BSH;            // 391
    int* hist   = offs + (N + 1);                // NB*nwg
    int* bsum   = hist + NB * nwg;               // 256
    unsigned* packed = (unsigned*)(bsum + 256);  // E
    int* perm   = (int*)(packed + E);            // E

    const int nb = (N + 63) / 64;
    const int gb = (N + 3) / 4;
    const int nh = NB * nwg;
    const int nsb = (nh + 1023) / 1024;

    // ---- CSR build: two-level multisplit (no global atomics) ----
    bin_hist<<<nwg, 256, 0, stream>>>(ei, hist, E, nwg, NB);
    greduce<<<nsb, 256, 0, stream>>>(hist, bsum, nh);
    scan_bsums<<<1, 256, 0, stream>>>(bsum, nsb);
    gapply<<<nsb, 256, 0, stream>>>(hist, bsum, nh);
    bin_scatter<<<nwg, 256, 0, stream>>>(ei, hist, packed, E, nwg, NB);
    bucket_sort<<<NB, 256, 0, stream>>>(packed, hist, offs, degf, perm, E, nwg, NB, N);

    pack_weights<<<256, 256, 0, stream>>>(lin_W, c1_Wl, c1_Wr, c2_Wl, c2_Wr, wp);

    // layer 1: h1 = relu(x @ lin_W^T + lin_b)   (f32 staged directly)
    gemm_lin<<<nb, 256, 0, stream>>>(x, wp, lin_b, h1, N);

    // conv1: agg = mean_{j->i} h1[j];  h2 = relu(agg @ Wl^T + b + h1 @ Wr^T)
    gather_mean_128<<<gb, 256, 0, stream>>>(h1, offs, perm, degf, aggb, N);
    gemm_c1<<<nb, 256, 0, stream>>>(aggb, h1, wp + 16384, wp + 32768, c1_bl, h2, N);

    // conv2: g2 = h2 @ Wl^T, r2 = h2 @ Wr^T + b (both bf16);
    // out = log_softmax(gather_mean(g2) + r2)
    gemm_dual<<<nb, 256, 0, stream>>>(h2, wp + 49152, wp + 57344, c2_bl, g2, r2, N);
    gather_out<<<gb, 256, 0, stream>>>(g2, r2, offs, perm, degf, out, N);
}